// Round 7
// baseline (254.924 us; speedup 1.0000x reference)
//
#include <hip/hip_runtime.h>
#include <math.h>

constexpr int B = 32;
constexpr int NN = 2048;   // nodes
constexpr int E = 65536;   // edges
constexpr float SLOPE = 0.01f;

typedef __attribute__((ext_vector_type(8))) short bf16x8;
typedef __attribute__((ext_vector_type(4))) float f32x4;

__device__ __forceinline__ float lrelu(float x) { return x > 0.f ? x : SLOPE * x; }
__device__ __forceinline__ int imin(int a, int b) { return a < b ? a : b; }

__device__ __forceinline__ unsigned int pack_bf16(float lo, float hi) {
    unsigned int a = __float_as_uint(lo);
    unsigned int b = __float_as_uint(hi);
    a += 0x7fffu + ((a >> 16) & 1u);
    b += 0x7fffu + ((b >> 16) & 1u);
    return (a >> 16) | (b & 0xffff0000u);
}

__device__ __forceinline__ unsigned short bf16_1(float x) {
    unsigned int u = __float_as_uint(x);
    u += 0x7fffu + ((u >> 16) & 1u);
    return (unsigned short)(u >> 16);
}

__device__ __forceinline__ float bf16_f(unsigned short s) {
    return __uint_as_float(((unsigned int)s) << 16);
}

__device__ __forceinline__ void unpack_bf16(unsigned int u, float& lo, float& hi) {
    lo = __uint_as_float(u << 16);
    hi = __uint_as_float(u & 0xffff0000u);
}

// ---------------- prep (blocks 8..11) + CSR-counter zero (blocks 0..7) ----------------
__global__ __launch_bounds__(256) void prep_zero_kernel(
    const float* __restrict__ W1c, const float* __restrict__ W2c,
    const float* __restrict__ W1v, const float* __restrict__ W2v,
    const float* __restrict__ W1e, const float* __restrict__ W2e,
    const float* __restrict__ W1o,
    float* __restrict__ W1cT, float* __restrict__ W2cT,
    float* __restrict__ W1vT, float* __restrict__ W2vT,
    float* __restrict__ W1sT, float* __restrict__ W1dT,
    unsigned short* __restrict__ W2eb, float* __restrict__ W1oT,
    int* __restrict__ cnt, int* __restrict__ cursor)
{
    int blk = blockIdx.x;
    if (blk < 8) {
        int i = blk * 256 + threadIdx.x;           // 0..2047
        cnt[i] = 0;
        cursor[i] = 0;
        return;
    }
    int t = (blk - 8) * 256 + threadIdx.x;         // 0..1023
    for (int i = t; i < 32 * 24; i += 1024) W1cT[(i % 24) * 32 + i / 24] = W1c[i];
    for (int i = t; i < 32 * 32; i += 1024) W2cT[(i % 32) * 32 + i / 32] = W2c[i];
    for (int i = t; i < 32 * 64; i += 1024) W1vT[(i % 64) * 32 + i / 64] = W1v[i];
    for (int i = t; i < 32 * 32; i += 1024) W2vT[(i % 32) * 32 + i / 32] = W2v[i];
    for (int i = t; i < 32 * 68; i += 1024) {
        int o = i / 68, j = i % 68;
        if (j < 34) W1sT[j * 32 + o] = W1e[i];
        else        W1dT[(j - 34) * 32 + o] = W1e[i];
    }
    for (int i = t; i < 32 * 32; i += 1024) {       // W2e row-major f32 -> bf16 (RNE)
        unsigned int u = __float_as_uint(W2e[i]);
        u += 0x7fffu + ((u >> 16) & 1u);
        W2eb[i] = (unsigned short)(u >> 16);
    }
    for (int i = t; i < 32 * 32; i += 1024) W1oT[(i % 32) * 32 + i / 32] = W1o[i];
}

// ---------------- CSR build ----------------
__global__ __launch_bounds__(256) void count_kernel(const int* __restrict__ edges, int* __restrict__ cnt)
{
    int e = blockIdx.x * 256 + threadIdx.x;
    if (e < E) atomicAdd(&cnt[edges[E + e]], 1);
}

__global__ __launch_bounds__(1024) void scan_kernel(const int* __restrict__ cnt, int* __restrict__ offs)
{
    __shared__ int s[1024];
    int t = threadIdx.x;
    int c0 = cnt[2 * t], c1 = cnt[2 * t + 1];
    int own = c0 + c1;
    s[t] = own;
    __syncthreads();
    int v = own;
    for (int d = 1; d < 1024; d <<= 1) {
        int add = (t >= d) ? s[t - d] : 0;
        __syncthreads();
        v += add;
        s[t] = v;
        __syncthreads();
    }
    int excl = v - own;
    offs[2 * t] = excl;
    offs[2 * t + 1] = excl + c0;
    if (t == 1023) offs[2048] = v;       // total = E
}

__global__ __launch_bounds__(256) void fill_kernel(
    const int* __restrict__ edges, const int* __restrict__ offs,
    int* __restrict__ cursor, int* __restrict__ elist)
{
    int e = blockIdx.x * 256 + threadIdx.x;
    if (e < E) {
        int d = edges[E + e];
        int p = atomicAdd(&cursor[d], 1);
        elist[offs[d] + p] = edges[e];
    }
}

// ---------------- vertex MLP + per-node edge-layer-1 projections ----------------
// 1 thread per node. Activations live in LDS as a per-thread COLUMN scratchpad
// (transposed [feat][tid] layout -> conflict-free, no cross-thread sharing, no
// barriers). j-loops stay ROLLED (unroll 2) so the code fits I$; accumulators
// are statically-indexed registers (rule #20); weights are uniform -> s_load.
__global__ __launch_bounds__(256) void vertex_kernel(
    const float* __restrict__ vert,
    const float* __restrict__ Wx,  const float* __restrict__ bx,
    const float* __restrict__ Wy,  const float* __restrict__ by,
    const float* __restrict__ Wth, const float* __restrict__ bth,
    const float* __restrict__ b1c, const float* __restrict__ b2c,
    const float* __restrict__ b1v, const float* __restrict__ b2v,
    const float* __restrict__ b1e,
    const float* __restrict__ W1cT, const float* __restrict__ W2cT,
    const float* __restrict__ W1vT, const float* __restrict__ W2vT,
    const float* __restrict__ W1sT, const float* __restrict__ W1dT,
    unsigned int* __restrict__ asrc, unsigned int* __restrict__ adst)
{
    __shared__ unsigned short sA[34 * 256];   // bf16 scratch (c / v1)
    __shared__ unsigned short sB[34 * 256];   // bf16 scratch (h / vfr)
    __shared__ float sCF[64 * 256];           // f32 cf buffer
    int t = threadIdx.x;
    int idx = blockIdx.x * 256 + t;
    const float* v = vert + (size_t)idx * 11;
    float qk0 = v[0], qk1 = v[1], qk2 = v[2];
    float q00 = v[3], q01 = v[4], q02 = v[5];
    float qg0 = v[6], qg1 = v[7], qg2 = v[8];
    float col0 = v[9], col1 = v[10];

    for (int half = 0; half < 2; ++half) {
        float a0 = half ? qg0 : q00;
        float a1 = half ? qg1 : q01;
        float a2 = half ? qg2 : q02;
        #pragma unroll
        for (int k = 0; k < 8; ++k) {
            sA[k * 256 + t]        = bf16_1(lrelu(qk0 * Wx[2 * k]  + a0 * Wx[2 * k + 1]  + bx[k]));
            sA[(8 + k) * 256 + t]  = bf16_1(lrelu(qk1 * Wy[2 * k]  + a1 * Wy[2 * k + 1]  + by[k]));
            sA[(16 + k) * 256 + t] = bf16_1(lrelu(qk2 * Wth[2 * k] + a2 * Wth[2 * k + 1] + bth[k]));
        }
        float h[32];
        #pragma unroll
        for (int o = 0; o < 32; ++o) h[o] = b1c[o];
        #pragma unroll 2
        for (int j = 0; j < 24; ++j) {
            float x = bf16_f(sA[j * 256 + t]);
            #pragma unroll
            for (int o = 0; o < 32; ++o) h[o] += x * W1cT[j * 32 + o];
        }
        #pragma unroll
        for (int o = 0; o < 32; ++o) sB[o * 256 + t] = bf16_1(lrelu(h[o]));

        float g[32];
        #pragma unroll
        for (int o = 0; o < 32; ++o) g[o] = b2c[o];
        #pragma unroll 2
        for (int j = 0; j < 32; ++j) {
            float x = bf16_f(sB[j * 256 + t]);
            #pragma unroll
            for (int o = 0; o < 32; ++o) g[o] += x * W2cT[j * 32 + o];
        }
        #pragma unroll
        for (int o = 0; o < 32; ++o) sCF[(half * 32 + o) * 256 + t] = lrelu(g[o]);
    }

    float v1[32];
    #pragma unroll
    for (int o = 0; o < 32; ++o) v1[o] = b1v[o];
    #pragma unroll 2
    for (int j = 0; j < 64; ++j) {
        float x = sCF[j * 256 + t];
        #pragma unroll
        for (int o = 0; o < 32; ++o) v1[o] += x * W1vT[j * 32 + o];
    }
    #pragma unroll
    for (int o = 0; o < 32; ++o) sA[o * 256 + t] = bf16_1(lrelu(v1[o]));

    float v2[32];
    #pragma unroll
    for (int o = 0; o < 32; ++o) v2[o] = b2v[o];
    #pragma unroll 2
    for (int j = 0; j < 32; ++j) {
        float x = bf16_f(sA[j * 256 + t]);
        #pragma unroll
        for (int o = 0; o < 32; ++o) v2[o] += x * W2vT[j * 32 + o];
    }
    #pragma unroll
    for (int o = 0; o < 32; ++o) sB[o * 256 + t] = bf16_1(lrelu(v2[o]));
    sB[32 * 256 + t] = bf16_1(col0);
    sB[33 * 256 + t] = bf16_1(col1);

    float as[32], ad[32];
    #pragma unroll
    for (int o = 0; o < 32; ++o) { as[o] = 0.f; ad[o] = b1e[o]; }
    #pragma unroll 2
    for (int j = 0; j < 34; ++j) {
        float x = bf16_f(sB[j * 256 + t]);
        #pragma unroll
        for (int o = 0; o < 32; ++o) {
            as[o] += x * W1sT[j * 32 + o];
            ad[o] += x * W1dT[j * 32 + o];
        }
    }

    unsigned int* ps = asrc + ((size_t)idx << 4);   // 16 uints = 32 bf16
    unsigned int* pd = adst + ((size_t)idx << 4);
    #pragma unroll
    for (int q = 0; q < 16; ++q) {
        ps[q] = pack_bf16(as[2 * q], as[2 * q + 1]);
        pd[q] = pack_bf16(ad[2 * q], ad[2 * q + 1]);
    }
}

// ---------------- edge phase: MFMA chunks, per-dst waves, XCD swizzle,
//                  depth-2 software-pipelined gathers, fused mean + node MLP ----------------
__global__ __launch_bounds__(256, 6) void edge_kernel(
    const unsigned int* __restrict__ asrc, const unsigned int* __restrict__ adst,
    const int* __restrict__ elist, const int* __restrict__ offs,
    const unsigned short* __restrict__ W2eb, const float* __restrict__ b2e,
    const float* __restrict__ W1oT, const float* __restrict__ b1o,
    const float* __restrict__ W2o,  const float* __restrict__ b2o,
    float* __restrict__ fv)
{
    constexpr int DPW = 8;                          // dsts per wave
    int logical = (blockIdx.x & 7) * 256 + (blockIdx.x >> 3);   // XCD swizzle
    int lane = threadIdx.x & 63;
    int gw = logical * 4 + (threadIdx.x >> 6);      // 8192 waves total
    int b = gw >> 8;                                // 256 waves per batch
    int d0 = (gw & 255) * DPW;
    int col = lane & 15;
    int grp = lane >> 4;
    const unsigned int* __restrict__ ab = asrc + (((size_t)b * NN) << 4) + grp * 4;
    const unsigned int* __restrict__ db = adst + (((size_t)b * NN) << 4) + grp * 4;

    union U8 { unsigned int u[4]; bf16x8 v; uint4 q; };
    U8 Bf0, Bf1;
    Bf0.q = *(const uint4*)(W2eb + col * 32 + grp * 8);
    Bf1.q = *(const uint4*)(W2eb + (col + 16) * 32 + grp * 8);
    float bias0 = b2e[col];
    float bias1 = b2e[col + 16];
    float w2oc = W2o[lane & 31];
    float b1oc = b1o[lane & 31];

    // ---- prologue: dst 0 bounds, first elist, first gather, adst row
    int start_c = offs[d0];
    int end_c = offs[d0 + 1];
    int src0 = (end_c > start_c) ? elist[imin(start_c + col, end_c - 1)] : 0;
    uint4 suA = *(const uint4*)(ab + ((size_t)src0 << 4));
    uint4 duA = *(const uint4*)(db + ((size_t)d0 << 4));

    for (int dd = 0; dd < DPW; ++dd) {
        int d = d0 + dd;
        int start = start_c, end = end_c;

        // prefetch next dst: bounds, first elist value, adst row (in flight
        // across this dst's whole chunk loop)
        int nstart = end, nend = end, srcN = 0;
        uint4 duN = {0, 0, 0, 0};
        if (dd + 1 < DPW) {
            nend = offs[d + 2];
            srcN = (nend > nstart) ? elist[imin(nstart + col, nend - 1)] : 0;
            duN = *(const uint4*)(db + ((size_t)(d + 1) << 4));
        }

        float adr[8];
        unpack_bf16(duA.x, adr[0], adr[1]);
        unpack_bf16(duA.y, adr[2], adr[3]);
        unpack_bf16(duA.z, adr[4], adr[5]);
        unpack_bf16(duA.w, adr[6], adr[7]);

        float s0 = 0.f, s1 = 0.f;
        uint4 su_cur = suA;
        int src_n = ((start + 16) < end) ? elist[imin(start + 16 + col, end - 1)] : 0;

        for (int e0 = start; e0 < end; e0 += 16) {
            bool have1 = (e0 + 16) < end;
            uint4 su_nxt = su_cur;
            if (have1) su_nxt = *(const uint4*)(ab + ((size_t)src_n << 4));   // gather i+1
            int src_n2 = ((e0 + 32) < end) ? elist[imin(e0 + 32 + col, end - 1)] : 0;  // elist i+2

            // compute chunk i from su_cur
            float h[8];
            {
                float lo, hi;
                unpack_bf16(su_cur.x, lo, hi);
                h[0] = fmaxf(lo + adr[0], 0.f); h[1] = fmaxf(hi + adr[1], 0.f);
                unpack_bf16(su_cur.y, lo, hi);
                h[2] = fmaxf(lo + adr[2], 0.f); h[3] = fmaxf(hi + adr[3], 0.f);
                unpack_bf16(su_cur.z, lo, hi);
                h[4] = fmaxf(lo + adr[4], 0.f); h[5] = fmaxf(hi + adr[5], 0.f);
                unpack_bf16(su_cur.w, lo, hi);
                h[6] = fmaxf(lo + adr[6], 0.f); h[7] = fmaxf(hi + adr[7], 0.f);
            }
            U8 A;
            A.u[0] = pack_bf16(h[0], h[1]);
            A.u[1] = pack_bf16(h[2], h[3]);
            A.u[2] = pack_bf16(h[4], h[5]);
            A.u[3] = pack_bf16(h[6], h[7]);

            f32x4 acc0 = {bias0, bias0, bias0, bias0};
            f32x4 acc1 = {bias1, bias1, bias1, bias1};
            acc0 = __builtin_amdgcn_mfma_f32_16x16x32_bf16(A.v, Bf0.v, acc0, 0, 0, 0);
            acc1 = __builtin_amdgcn_mfma_f32_16x16x32_bf16(A.v, Bf1.v, acc1, 0, 0, 0);

            int rowbase = e0 + grp * 4;
            #pragma unroll
            for (int r = 0; r < 4; ++r) {
                bool valid = (rowbase + r) < end;
                s0 += valid ? lrelu(acc0[r]) : 0.f;
                s1 += valid ? lrelu(acc1[r]) : 0.f;
            }
            su_cur = su_nxt;
            src_n = src_n2;
        }

        // seed next dst's first gather BEFORE the epilogue so the ~200cy of
        // shfl/FMA below hides its latency
        if (dd + 1 < DPW) {
            suA = *(const uint4*)(ab + ((size_t)srcN << 4));
            duA = duN;
            start_c = nstart;
            end_c = nend;
        }

        // reduce across the 4 lane-groups
        s0 += __shfl_xor(s0, 16); s0 += __shfl_xor(s0, 32);
        s1 += __shfl_xor(s1, 16); s1 += __shfl_xor(s1, 32);

        // fused node MLP: agg -> W1o/relu -> W2o dot -> lrelu
        int deg = end - start;
        float inv = 1.f / fmaxf((float)deg, 1.f);
        float a0 = s0 * inv;
        float a1 = s1 * inv;
        int o = lane & 31;
        float f1 = b1oc;
        #pragma unroll
        for (int j = 0; j < 16; ++j) {
            float aj = __shfl(a0, j);
            f1 += aj * W1oT[j * 32 + o];
            float ak = __shfl(a1, j);
            f1 += ak * W1oT[(16 + j) * 32 + o];
        }
        float tt = fmaxf(f1, 0.f) * w2oc;
        tt += __shfl_xor(tt, 1);
        tt += __shfl_xor(tt, 2);
        tt += __shfl_xor(tt, 4);
        tt += __shfl_xor(tt, 8);
        tt += __shfl_xor(tt, 16);
        if (lane == 0) fv[(size_t)b * NN + d] = lrelu(tt + b2o[0]);
    }
}

// ---------------- final: out[b] = sigmoid(dot(fv[b,:], Wg) + bg) ----------------
__global__ __launch_bounds__(256) void final_kernel(
    const float* __restrict__ fv, const float* __restrict__ Wg,
    const float* __restrict__ bg, float* __restrict__ out)
{
    int b = blockIdx.x;
    int t = threadIdx.x;
    float p = 0.f;
    for (int n = t; n < NN; n += 256) p += fv[(size_t)b * NN + n] * Wg[n];
    __shared__ float red[256];
    red[t] = p;
    __syncthreads();
    for (int s = 128; s > 0; s >>= 1) {
        if (t < s) red[t] += red[t + s];
        __syncthreads();
    }
    if (t == 0) {
        float x = red[0] + bg[0];
        out[b] = 1.f / (1.f + expf(-x));
    }
}

extern "C" void kernel_launch(void* const* d_in, const int* in_sizes, int n_in,
                              void* d_out, int out_size, void* d_ws, size_t ws_size,
                              hipStream_t stream)
{
    const float* vert = (const float*)d_in[0];
    const int*   edges = (const int*)d_in[1];
    const float* Wx  = (const float*)d_in[2];
    const float* bx  = (const float*)d_in[3];
    const float* Wy  = (const float*)d_in[4];
    const float* by  = (const float*)d_in[5];
    const float* Wth = (const float*)d_in[6];
    const float* bth = (const float*)d_in[7];
    const float* W1c = (const float*)d_in[8];
    const float* b1c = (const float*)d_in[9];
    const float* W2c = (const float*)d_in[10];
    const float* b2c = (const float*)d_in[11];
    const float* W1v = (const float*)d_in[12];
    const float* b1v = (const float*)d_in[13];
    const float* W2v = (const float*)d_in[14];
    const float* b2v = (const float*)d_in[15];
    const float* W1e = (const float*)d_in[16];
    const float* b1e = (const float*)d_in[17];
    const float* W2e = (const float*)d_in[18];
    const float* b2e = (const float*)d_in[19];
    const float* W1o = (const float*)d_in[20];
    const float* b1o = (const float*)d_in[21];
    const float* W2o = (const float*)d_in[22];
    const float* b2o = (const float*)d_in[23];
    const float* Wg  = (const float*)d_in[24];
    const float* bg  = (const float*)d_in[25];
    float* out = (float*)d_out;

    // workspace layout (~9 MB, all chunks 16B-aligned)
    char* w = (char*)d_ws;
    unsigned int* asrc = (unsigned int*)w; w += (size_t)B * NN * 32 * 2;  // bf16 pairs
    unsigned int* adst = (unsigned int*)w; w += (size_t)B * NN * 32 * 2;
    float* fv   = (float*)w; w += (size_t)B * NN * 4;
    float* W1cT = (float*)w; w += 32 * 24 * 4;
    float* W2cT = (float*)w; w += 32 * 32 * 4;
    float* W1vT = (float*)w; w += 32 * 64 * 4;
    float* W2vT = (float*)w; w += 32 * 32 * 4;
    float* W1sT = (float*)w; w += 34 * 32 * 4;
    float* W1dT = (float*)w; w += 34 * 32 * 4;
    float* W1oT = (float*)w; w += 32 * 32 * 4;
    unsigned short* W2eb = (unsigned short*)w; w += 32 * 32 * 2;
    int* cnt    = (int*)w;   w += NN * 4;
    int* cursor = (int*)w;   w += NN * 4;
    int* offs   = (int*)w;   w += 2052 * 4;          // NN+1 used, padded to 16B
    int* elist  = (int*)w;   w += E * 4;

    prep_zero_kernel<<<12, 256, 0, stream>>>(W1c, W2c, W1v, W2v, W1e, W2e, W1o,
                                             W1cT, W2cT, W1vT, W2vT, W1sT, W1dT,
                                             W2eb, W1oT, cnt, cursor);
    count_kernel<<<E / 256, 256, 0, stream>>>(edges, cnt);
    scan_kernel<<<1, 1024, 0, stream>>>(cnt, offs);
    fill_kernel<<<E / 256, 256, 0, stream>>>(edges, offs, cursor, elist);

    vertex_kernel<<<(B * NN) / 256, 256, 0, stream>>>(
        vert, Wx, bx, Wy, by, Wth, bth, b1c, b2c, b1v, b2v, b1e,
        W1cT, W2cT, W1vT, W2vT, W1sT, W1dT, asrc, adst);

    edge_kernel<<<(B * NN / 8) / 4, 256, 0, stream>>>(
        asrc, adst, elist, offs, W2eb, b2e, W1oT, b1o, W2o, b2o, fv);

    final_kernel<<<B, 256, 0, stream>>>(fv, Wg, bg, out);
}

// Round 9
// 239.330 us; speedup vs baseline: 1.0652x; 1.0652x over previous
//
#include <hip/hip_runtime.h>
#include <math.h>

constexpr int B = 32;
constexpr int NN = 2048;   // nodes
constexpr int E = 65536;   // edges
constexpr float SLOPE = 0.01f;

typedef __attribute__((ext_vector_type(8))) short bf16x8;
typedef __attribute__((ext_vector_type(4))) float f32x4;

__device__ __forceinline__ float lrelu(float x) { return x > 0.f ? x : SLOPE * x; }
__device__ __forceinline__ int imin(int a, int b) { return a < b ? a : b; }

__device__ __forceinline__ unsigned int pack_bf16(float lo, float hi) {
    unsigned int a = __float_as_uint(lo);
    unsigned int b = __float_as_uint(hi);
    a += 0x7fffu + ((a >> 16) & 1u);
    b += 0x7fffu + ((b >> 16) & 1u);
    return (a >> 16) | (b & 0xffff0000u);
}

__device__ __forceinline__ void unpack_bf16(unsigned int u, float& lo, float& hi) {
    lo = __uint_as_float(u << 16);
    hi = __uint_as_float(u & 0xffff0000u);
}

__device__ __forceinline__ void unpack8(const uint4& u, float f[8]) {
    unpack_bf16(u.x, f[0], f[1]);
    unpack_bf16(u.y, f[2], f[3]);
    unpack_bf16(u.z, f[4], f[5]);
    unpack_bf16(u.w, f[6], f[7]);
}

// 8-feature group FMA: one LDS b128 read amortized over 256 static FMAs.
// jj is runtime (rolled loop) -> W offset stays scalar (SGPR) since Wt is uniform.
__device__ __forceinline__ void fma_grp(const float* __restrict__ Wt, int jj,
                                        const uint4& r, float acc[32]) {
    float x[8]; unpack8(r, x);
    const float* Wp = Wt + jj * 256;
    #pragma unroll
    for (int jo = 0; jo < 8; ++jo) {
        #pragma unroll
        for (int o = 0; o < 32; ++o) acc[o] += x[jo] * Wp[jo * 32 + o];
    }
}

__device__ __forceinline__ void fma_grp2(const float* __restrict__ Ws,
                                         const float* __restrict__ Wd, int jj,
                                         const uint4& r, float a1[32], float a2[32]) {
    float x[8]; unpack8(r, x);
    const float* Wps = Ws + jj * 256;
    const float* Wpd = Wd + jj * 256;
    #pragma unroll
    for (int jo = 0; jo < 8; ++jo) {
        #pragma unroll
        for (int o = 0; o < 32; ++o) a1[o] += x[jo] * Wps[jo * 32 + o];
        #pragma unroll
        for (int o = 0; o < 32; ++o) a2[o] += x[jo] * Wpd[jo * 32 + o];
    }
}

// rolled layer driver, 2-deep register rotation (read jj+1 while FMA'ing jj)
__device__ __forceinline__ void layerN(const unsigned short* col, int G,
                                       const float* __restrict__ Wt, float acc[32]) {
    uint4 cur = *(const uint4*)col;
    #pragma unroll 1
    for (int jj = 0; jj < G; ++jj) {
        uint4 nxt = (jj + 1 < G) ? *(const uint4*)(col + (jj + 1) * 8) : cur;
        fma_grp(Wt, jj, cur, acc);
        cur = nxt;
    }
}

__device__ __forceinline__ void layer2N(const unsigned short* col, int G,
                                        const float* __restrict__ Ws,
                                        const float* __restrict__ Wd,
                                        float a1[32], float a2[32]) {
    uint4 cur = *(const uint4*)col;
    #pragma unroll 1
    for (int jj = 0; jj < G; ++jj) {
        uint4 nxt = (jj + 1 < G) ? *(const uint4*)(col + (jj + 1) * 8) : cur;
        fma_grp2(Ws, Wd, jj, cur, a1, a2);
        cur = nxt;
    }
}

// ---------------- prep (blocks 8..11) + CSR-counter zero (blocks 0..7) ----------------
__global__ __launch_bounds__(256) void prep_zero_kernel(
    const float* __restrict__ W1c, const float* __restrict__ W2c,
    const float* __restrict__ W1v, const float* __restrict__ W2v,
    const float* __restrict__ W1e, const float* __restrict__ W2e,
    const float* __restrict__ W1o,
    float* __restrict__ W1cT, float* __restrict__ W2cT,
    float* __restrict__ W1vT, float* __restrict__ W2vT,
    float* __restrict__ W1sT, float* __restrict__ W1dT,
    unsigned short* __restrict__ W2eb, float* __restrict__ W1oT,
    int* __restrict__ cnt, int* __restrict__ cursor)
{
    int blk = blockIdx.x;
    if (blk < 8) {
        int i = blk * 256 + threadIdx.x;
        cnt[i] = 0;
        cursor[i] = 0;
        return;
    }
    int t = (blk - 8) * 256 + threadIdx.x;         // 0..1023
    for (int i = t; i < 32 * 24; i += 1024) W1cT[(i % 24) * 32 + i / 24] = W1c[i];
    for (int i = t; i < 32 * 32; i += 1024) W2cT[(i % 32) * 32 + i / 32] = W2c[i];
    for (int i = t; i < 32 * 64; i += 1024) W1vT[(i % 64) * 32 + i / 64] = W1v[i];
    for (int i = t; i < 32 * 32; i += 1024) W2vT[(i % 32) * 32 + i / 32] = W2v[i];
    for (int i = t; i < 32 * 68; i += 1024) {
        int o = i / 68, j = i % 68;
        if (j < 34) W1sT[j * 32 + o] = W1e[i];
        else        W1dT[(j - 34) * 32 + o] = W1e[i];
    }
    for (int i = t; i < 32 * 32; i += 1024) {
        unsigned int u = __float_as_uint(W2e[i]);
        u += 0x7fffu + ((u >> 16) & 1u);
        W2eb[i] = (unsigned short)(u >> 16);
    }
    for (int i = t; i < 32 * 32; i += 1024) W1oT[(i % 32) * 32 + i / 32] = W1o[i];
}

// ---------------- CSR build ----------------
__global__ __launch_bounds__(256) void count_kernel(const int* __restrict__ edges, int* __restrict__ cnt)
{
    int e = blockIdx.x * 256 + threadIdx.x;
    if (e < E) atomicAdd(&cnt[edges[E + e]], 1);
}

__global__ __launch_bounds__(1024) void scan_kernel(const int* __restrict__ cnt, int* __restrict__ offs)
{
    __shared__ int s[1024];
    int t = threadIdx.x;
    int c0 = cnt[2 * t], c1 = cnt[2 * t + 1];
    int own = c0 + c1;
    s[t] = own;
    __syncthreads();
    int v = own;
    for (int d = 1; d < 1024; d <<= 1) {
        int add = (t >= d) ? s[t - d] : 0;
        __syncthreads();
        v += add;
        s[t] = v;
        __syncthreads();
    }
    int excl = v - own;
    offs[2 * t] = excl;
    offs[2 * t + 1] = excl + c0;
    if (t == 1023) offs[2048] = v;
}

__global__ __launch_bounds__(256) void fill_kernel(
    const int* __restrict__ edges, const int* __restrict__ offs,
    int* __restrict__ cursor, int* __restrict__ elist)
{
    int e = blockIdx.x * 256 + threadIdx.x;
    if (e < E) {
        int d = edges[E + e];
        int p = atomicAdd(&cursor[d], 1);
        elist[offs[d] + p] = edges[e];
    }
}

// ---------------- vertex MLP + projections: LDS column scratch, b128 batched reads ----------------
// Per-thread private LDS columns (no cross-thread sharing; DS ops are in-order per
// wave so no barriers). bufA stride 144B / bufB stride 80B -> conflict-free b128 reads.
__global__ __launch_bounds__(256) void vertex_kernel(
    const float* __restrict__ vert,
    const float* __restrict__ Wx,  const float* __restrict__ bx,
    const float* __restrict__ Wy,  const float* __restrict__ by,
    const float* __restrict__ Wth, const float* __restrict__ bth,
    const float* __restrict__ b1c, const float* __restrict__ b2c,
    const float* __restrict__ b1v, const float* __restrict__ b2v,
    const float* __restrict__ b1e,
    const float* __restrict__ W1cT, const float* __restrict__ W2cT,
    const float* __restrict__ W1vT, const float* __restrict__ W2vT,
    const float* __restrict__ W1sT, const float* __restrict__ W1dT,
    unsigned int* __restrict__ asrc, unsigned int* __restrict__ adst)
{
    __shared__ unsigned short bufA[256 * 72];   // 36.9 KB (holds up to 64 feats)
    __shared__ unsigned short bufB[256 * 40];   // 20.5 KB (holds up to 32 feats)
    int t = threadIdx.x;
    unsigned short* Ac = bufA + t * 72;
    unsigned short* Bc = bufB + t * 40;
    int idx = blockIdx.x * 256 + t;
    const float* v = vert + (size_t)idx * 11;
    float qk0 = v[0], qk1 = v[1], qk2 = v[2];
    float q00 = v[3], q01 = v[4], q02 = v[5];
    float qg0 = v[6], qg1 = v[7], qg2 = v[8];
    float col0 = v[9], col1 = v[10];

    for (int half = 0; half < 2; ++half) {
        float a0 = half ? qg0 : q00;
        float a1 = half ? qg1 : q01;
        float a2 = half ? qg2 : q02;
        // pair features -> bufA feats 0..23 (bf16 pairs)
        #pragma unroll
        for (int i = 0; i < 4; ++i) {
            ((unsigned int*)Ac)[i] = pack_bf16(
                lrelu(qk0 * Wx[4 * i]     + a0 * Wx[4 * i + 1] + bx[2 * i]),
                lrelu(qk0 * Wx[4 * i + 2] + a0 * Wx[4 * i + 3] + bx[2 * i + 1]));
            ((unsigned int*)Ac)[4 + i] = pack_bf16(
                lrelu(qk1 * Wy[4 * i]     + a1 * Wy[4 * i + 1] + by[2 * i]),
                lrelu(qk1 * Wy[4 * i + 2] + a1 * Wy[4 * i + 3] + by[2 * i + 1]));
            ((unsigned int*)Ac)[8 + i] = pack_bf16(
                lrelu(qk2 * Wth[4 * i]     + a2 * Wth[4 * i + 1] + bth[2 * i]),
                lrelu(qk2 * Wth[4 * i + 2] + a2 * Wth[4 * i + 3] + bth[2 * i + 1]));
        }
        float h[32];
        #pragma unroll
        for (int o = 0; o < 32; ++o) h[o] = b1c[o];
        layerN(Ac, 3, W1cT, h);                          // 24 feats
        #pragma unroll
        for (int i = 0; i < 16; ++i)
            ((unsigned int*)Bc)[i] = pack_bf16(lrelu(h[2 * i]), lrelu(h[2 * i + 1]));

        float g[32];
        #pragma unroll
        for (int o = 0; o < 32; ++o) g[o] = b2c[o];
        layerN(Bc, 4, W2cT, g);                          // 32 feats
        #pragma unroll
        for (int i = 0; i < 16; ++i)                     // cf half -> bufA[half*32..]
            ((unsigned int*)Ac)[half * 16 + i] = pack_bf16(lrelu(g[2 * i]), lrelu(g[2 * i + 1]));
    }

    float v1[32];
    #pragma unroll
    for (int o = 0; o < 32; ++o) v1[o] = b1v[o];
    layerN(Ac, 8, W1vT, v1);                             // 64 feats
    #pragma unroll
    for (int i = 0; i < 16; ++i)
        ((unsigned int*)Bc)[i] = pack_bf16(lrelu(v1[2 * i]), lrelu(v1[2 * i + 1]));

    float v2[32];
    #pragma unroll
    for (int o = 0; o < 32; ++o) v2[o] = b2v[o];
    layerN(Bc, 4, W2vT, v2);                             // 32 feats
    #pragma unroll
    for (int i = 0; i < 16; ++i)                         // vfr[0..31] (col0/col1 stay in regs)
        ((unsigned int*)Bc)[i] = pack_bf16(lrelu(v2[2 * i]), lrelu(v2[2 * i + 1]));

    float as[32], ad[32];
    #pragma unroll
    for (int o = 0; o < 32; ++o) { as[o] = 0.f; ad[o] = b1e[o]; }
    layer2N(Bc, 4, W1sT, W1dT, as, ad);                  // 32 feats
    #pragma unroll
    for (int o = 0; o < 32; ++o) {                       // feats 32,33 = col0,col1 (static)
        as[o] += col0 * W1sT[32 * 32 + o] + col1 * W1sT[33 * 32 + o];
        ad[o] += col0 * W1dT[32 * 32 + o] + col1 * W1dT[33 * 32 + o];
    }

    unsigned int* ps = asrc + ((size_t)idx << 4);
    unsigned int* pd = adst + ((size_t)idx << 4);
    #pragma unroll
    for (int q = 0; q < 16; ++q) {
        ps[q] = pack_bf16(as[2 * q], as[2 * q + 1]);
        pd[q] = pack_bf16(ad[2 * q], ad[2 * q + 1]);
    }
}

// ---------------- edge phase: LDS-staged asrc table, per-segment blocks ----------------
// Grid = 32 batches x 8 dst-segments. Block stages its batch's full asrc (128 KB)
// into LDS, then each wave owns 64 consecutive dsts. Gathers hit LDS (zero L2
// pollution); depth-2 pipeline on (elist global, gather LDS). XCD swizzle
// co-locates a batch's 8 blocks on one XCD so staging re-reads hit that L2.
__global__ __launch_bounds__(256) void edge_kernel(
    const unsigned int* __restrict__ asrc, const unsigned int* __restrict__ adst,
    const int* __restrict__ elist, const int* __restrict__ offs,
    const unsigned short* __restrict__ W2eb, const float* __restrict__ b2e,
    const float* __restrict__ W1oT, const float* __restrict__ b1o,
    const float* __restrict__ W2o,  const float* __restrict__ b2o,
    float* __restrict__ fv)
{
    __shared__ uint4 sA[NN * 4];                    // 128 KB: asrc[b], row n = sA[n*4 + grp]
    int logical = (blockIdx.x & 7) * 32 + (blockIdx.x >> 3);
    int b = logical >> 3;                           // batch  (4 consecutive per XCD)
    int seg = logical & 7;                          // dst segment
    int tid = threadIdx.x;
    int wv = tid >> 6;
    int lane = tid & 63;
    int col = lane & 15;
    int grp = lane >> 4;

    // ---- stage asrc[b] -> LDS (coalesced uint4 stream)
    const uint4* gsrc = (const uint4*)(asrc + (((size_t)b * NN) << 4));
    #pragma unroll 4
    for (int i = tid; i < NN * 4; i += 256) sA[i] = gsrc[i];
    __syncthreads();

    union U8 { unsigned int u[4]; bf16x8 v; uint4 q; };
    U8 Bf0, Bf1;
    Bf0.q = *(const uint4*)(W2eb + col * 32 + grp * 8);
    Bf1.q = *(const uint4*)(W2eb + (col + 16) * 32 + grp * 8);
    float bias0 = b2e[col];
    float bias1 = b2e[col + 16];
    float w2oc = W2o[lane & 31];
    float b1oc = b1o[lane & 31];
    float b2oc = b2o[0];
    const unsigned int* adb = adst + (((size_t)b * NN) << 4) + grp * 4;

    int dbase = seg * 256 + wv * 64;
    for (int dd = 0; dd < 64; ++dd) {
        int d = dbase + dd;
        int start = offs[d];
        int end = offs[d + 1];

        const uint4 du = *(const uint4*)(adb + ((size_t)d << 4));
        float adr[8]; unpack8(du, adr);

        float s0 = 0.f, s1 = 0.f;
        if (end > start) {
            int src_c = elist[imin(start + col, end - 1)];
            uint4 su_c = sA[src_c * 4 + grp];
            int src_n = (start + 16 < end) ? elist[imin(start + 16 + col, end - 1)] : 0;

            for (int e0 = start; e0 < end; e0 += 16) {
                uint4 su_n = (e0 + 16 < end) ? sA[src_n * 4 + grp] : su_c;   // LDS prefetch i+1
                src_n = (e0 + 32 < end) ? elist[imin(e0 + 32 + col, end - 1)] : 0;  // elist i+2

                float h[8];
                {
                    float lo, hi;
                    unpack_bf16(su_c.x, lo, hi);
                    h[0] = fmaxf(lo + adr[0], 0.f); h[1] = fmaxf(hi + adr[1], 0.f);
                    unpack_bf16(su_c.y, lo, hi);
                    h[2] = fmaxf(lo + adr[2], 0.f); h[3] = fmaxf(hi + adr[3], 0.f);
                    unpack_bf16(su_c.z, lo, hi);
                    h[4] = fmaxf(lo + adr[4], 0.f); h[5] = fmaxf(hi + adr[5], 0.f);
                    unpack_bf16(su_c.w, lo, hi);
                    h[6] = fmaxf(lo + adr[6], 0.f); h[7] = fmaxf(hi + adr[7], 0.f);
                }
                U8 A;
                A.u[0] = pack_bf16(h[0], h[1]);
                A.u[1] = pack_bf16(h[2], h[3]);
                A.u[2] = pack_bf16(h[4], h[5]);
                A.u[3] = pack_bf16(h[6], h[7]);

                f32x4 acc0 = {bias0, bias0, bias0, bias0};
                f32x4 acc1 = {bias1, bias1, bias1, bias1};
                acc0 = __builtin_amdgcn_mfma_f32_16x16x32_bf16(A.v, Bf0.v, acc0, 0, 0, 0);
                acc1 = __builtin_amdgcn_mfma_f32_16x16x32_bf16(A.v, Bf1.v, acc1, 0, 0, 0);

                int rowbase = e0 + grp * 4;
                #pragma unroll
                for (int r = 0; r < 4; ++r) {
                    bool valid = (rowbase + r) < end;
                    s0 += valid ? lrelu(acc0[r]) : 0.f;
                    s1 += valid ? lrelu(acc1[r]) : 0.f;
                }
                su_c = su_n;
            }
        }

        s0 += __shfl_xor(s0, 16); s0 += __shfl_xor(s0, 32);
        s1 += __shfl_xor(s1, 16); s1 += __shfl_xor(s1, 32);

        float inv = 1.f / fmaxf((float)(end - start), 1.f);
        float a0 = s0 * inv;
        float a1 = s1 * inv;
        int o = lane & 31;
        float f1 = b1oc;
        #pragma unroll
        for (int j = 0; j < 16; ++j) {
            float aj = __shfl(a0, j);
            f1 += aj * W1oT[j * 32 + o];
            float ak = __shfl(a1, j);
            f1 += ak * W1oT[(16 + j) * 32 + o];
        }
        float tt = fmaxf(f1, 0.f) * w2oc;
        tt += __shfl_xor(tt, 1);
        tt += __shfl_xor(tt, 2);
        tt += __shfl_xor(tt, 4);
        tt += __shfl_xor(tt, 8);
        tt += __shfl_xor(tt, 16);
        if (lane == 0) fv[(size_t)b * NN + d] = lrelu(tt + b2oc);
    }
}

// ---------------- final: out[b] = sigmoid(dot(fv[b,:], Wg) + bg) ----------------
__global__ __launch_bounds__(256) void final_kernel(
    const float* __restrict__ fv, const float* __restrict__ Wg,
    const float* __restrict__ bg, float* __restrict__ out)
{
    int b = blockIdx.x;
    int t = threadIdx.x;
    float p = 0.f;
    for (int n = t; n < NN; n += 256) p += fv[(size_t)b * NN + n] * Wg[n];
    __shared__ float red[256];
    red[t] = p;
    __syncthreads();
    for (int s = 128; s > 0; s >>= 1) {
        if (t < s) red[t] += red[t + s];
        __syncthreads();
    }
    if (t == 0) {
        float x = red[0] + bg[0];
        out[b] = 1.f / (1.f + expf(-x));
    }
}

extern "C" void kernel_launch(void* const* d_in, const int* in_sizes, int n_in,
                              void* d_out, int out_size, void* d_ws, size_t ws_size,
                              hipStream_t stream)
{
    const float* vert = (const float*)d_in[0];
    const int*   edges = (const int*)d_in[1];
    const float* Wx  = (const float*)d_in[2];
    const float* bx  = (const float*)d_in[3];
    const float* Wy  = (const float*)d_in[4];
    const float* by  = (const float*)d_in[5];
    const float* Wth = (const float*)d_in[6];
    const float* bth = (const float*)d_in[7];
    const float* W1c = (const float*)d_in[8];
    const float* b1c = (const float*)d_in[9];
    const float* W2c = (const float*)d_in[10];
    const float* b2c = (const float*)d_in[11];
    const float* W1v = (const float*)d_in[12];
    const float* b1v = (const float*)d_in[13];
    const float* W2v = (const float*)d_in[14];
    const float* b2v = (const float*)d_in[15];
    const float* W1e = (const float*)d_in[16];
    const float* b1e = (const float*)d_in[17];
    const float* W2e = (const float*)d_in[18];
    const float* b2e = (const float*)d_in[19];
    const float* W1o = (const float*)d_in[20];
    const float* b1o = (const float*)d_in[21];
    const float* W2o = (const float*)d_in[22];
    const float* b2o = (const float*)d_in[23];
    const float* Wg  = (const float*)d_in[24];
    const float* bg  = (const float*)d_in[25];
    float* out = (float*)d_out;

    // workspace layout (~9 MB, all chunks 16B-aligned)
    char* w = (char*)d_ws;
    unsigned int* asrc = (unsigned int*)w; w += (size_t)B * NN * 32 * 2;  // bf16 pairs
    unsigned int* adst = (unsigned int*)w; w += (size_t)B * NN * 32 * 2;
    float* fv   = (float*)w; w += (size_t)B * NN * 4;
    float* W1cT = (float*)w; w += 32 * 24 * 4;
    float* W2cT = (float*)w; w += 32 * 32 * 4;
    float* W1vT = (float*)w; w += 32 * 64 * 4;
    float* W2vT = (float*)w; w += 32 * 32 * 4;
    float* W1sT = (float*)w; w += 34 * 32 * 4;
    float* W1dT = (float*)w; w += 34 * 32 * 4;
    float* W1oT = (float*)w; w += 32 * 32 * 4;
    unsigned short* W2eb = (unsigned short*)w; w += 32 * 32 * 2;
    int* cnt    = (int*)w;   w += NN * 4;
    int* cursor = (int*)w;   w += NN * 4;
    int* offs   = (int*)w;   w += 2052 * 4;
    int* elist  = (int*)w;   w += E * 4;

    prep_zero_kernel<<<12, 256, 0, stream>>>(W1c, W2c, W1v, W2v, W1e, W2e, W1o,
                                             W1cT, W2cT, W1vT, W2vT, W1sT, W1dT,
                                             W2eb, W1oT, cnt, cursor);
    count_kernel<<<E / 256, 256, 0, stream>>>(edges, cnt);
    scan_kernel<<<1, 1024, 0, stream>>>(cnt, offs);
    fill_kernel<<<E / 256, 256, 0, stream>>>(edges, offs, cursor, elist);

    vertex_kernel<<<(B * NN) / 256, 256, 0, stream>>>(
        vert, Wx, bx, Wy, by, Wth, bth, b1c, b2c, b1v, b2v, b1e,
        W1cT, W2cT, W1vT, W2vT, W1sT, W1dT, asrc, adst);

    edge_kernel<<<B * 8, 256, 0, stream>>>(
        asrc, adst, elist, offs, W2eb, b2e, W1oT, b1o, W2o, b2o, fv);

    final_kernel<<<B, 256, 0, stream>>>(fv, Wg, bg, out);
}

// Round 10
// 127.223 us; speedup vs baseline: 2.0038x; 1.8812x over previous
//
#include <hip/hip_runtime.h>
#include <math.h>

constexpr int B = 32;
constexpr int NN = 2048;   // nodes
constexpr int E = 65536;   // edges
constexpr float SLOPE = 0.01f;

typedef __attribute__((ext_vector_type(8))) short bf16x8;
typedef __attribute__((ext_vector_type(4))) float f32x4;

__device__ __forceinline__ float lrelu(float x) { return x > 0.f ? x : SLOPE * x; }
__device__ __forceinline__ int imin(int a, int b) { return a < b ? a : b; }

__device__ __forceinline__ unsigned int pack_bf16(float lo, float hi) {
    unsigned int a = __float_as_uint(lo);
    unsigned int b = __float_as_uint(hi);
    a += 0x7fffu + ((a >> 16) & 1u);
    b += 0x7fffu + ((b >> 16) & 1u);
    return (a >> 16) | (b & 0xffff0000u);
}

__device__ __forceinline__ void unpack_bf16(unsigned int u, float& lo, float& hi) {
    lo = __uint_as_float(u << 16);
    hi = __uint_as_float(u & 0xffff0000u);
}

__device__ __forceinline__ void unpack8(const uint4& u, float f[8]) {
    unpack_bf16(u.x, f[0], f[1]);
    unpack_bf16(u.y, f[2], f[3]);
    unpack_bf16(u.z, f[4], f[5]);
    unpack_bf16(u.w, f[6], f[7]);
}

// ---- 16-output-half layer helpers (o0 is wave-uniform SGPR via readfirstlane) ----
__device__ __forceinline__ void fma_grp16(const float* __restrict__ Wt, int jj, int o0,
                                          const uint4& r, float acc[16]) {
    float x[8]; unpack8(r, x);
    const float* Wp = Wt + jj * 256 + o0;
    #pragma unroll
    for (int jo = 0; jo < 8; ++jo) {
        #pragma unroll
        for (int o = 0; o < 16; ++o) acc[o] += x[jo] * Wp[jo * 32 + o];
    }
}

__device__ __forceinline__ void layerN16(const unsigned short* col, int G, int o0,
                                         const float* __restrict__ Wt, float acc[16]) {
    uint4 cur = *(const uint4*)col;
    #pragma unroll 1
    for (int jj = 0; jj < G; ++jj) {
        uint4 nxt = (jj + 1 < G) ? *(const uint4*)(col + (jj + 1) * 8) : cur;
        fma_grp16(Wt, jj, o0, cur, acc);
        cur = nxt;
    }
}

__device__ __forceinline__ void layer2N16(const unsigned short* col, int G, int o0,
                                          const float* __restrict__ Ws,
                                          const float* __restrict__ Wd,
                                          float a1[16], float a2[16]) {
    uint4 cur = *(const uint4*)col;
    #pragma unroll 1
    for (int jj = 0; jj < G; ++jj) {
        uint4 nxt = (jj + 1 < G) ? *(const uint4*)(col + (jj + 1) * 8) : cur;
        float x[8]; unpack8(cur, x);
        const float* Wps = Ws + jj * 256 + o0;
        const float* Wpd = Wd + jj * 256 + o0;
        #pragma unroll
        for (int jo = 0; jo < 8; ++jo) {
            #pragma unroll
            for (int o = 0; o < 16; ++o) a1[o] += x[jo] * Wps[jo * 32 + o];
            #pragma unroll
            for (int o = 0; o < 16; ++o) a2[o] += x[jo] * Wpd[jo * 32 + o];
        }
        cur = nxt;
    }
}

// ---------------- prep (blocks 8..11) + CSR-counter zero (blocks 0..7) ----------------
__global__ __launch_bounds__(256) void prep_zero_kernel(
    const float* __restrict__ W1c, const float* __restrict__ W2c,
    const float* __restrict__ W1v, const float* __restrict__ W2v,
    const float* __restrict__ W1e, const float* __restrict__ W2e,
    const float* __restrict__ W1o,
    float* __restrict__ W1cT, float* __restrict__ W2cT,
    float* __restrict__ W1vT, float* __restrict__ W2vT,
    float* __restrict__ W1sT, float* __restrict__ W1dT,
    unsigned short* __restrict__ W2eb, float* __restrict__ W1oT,
    int* __restrict__ cnt, int* __restrict__ cursor)
{
    int blk = blockIdx.x;
    if (blk < 8) {
        int i = blk * 256 + threadIdx.x;
        cnt[i] = 0;
        cursor[i] = 0;
        return;
    }
    int t = (blk - 8) * 256 + threadIdx.x;         // 0..1023
    for (int i = t; i < 32 * 24; i += 1024) W1cT[(i % 24) * 32 + i / 24] = W1c[i];
    for (int i = t; i < 32 * 32; i += 1024) W2cT[(i % 32) * 32 + i / 32] = W2c[i];
    for (int i = t; i < 32 * 64; i += 1024) W1vT[(i % 64) * 32 + i / 64] = W1v[i];
    for (int i = t; i < 32 * 32; i += 1024) W2vT[(i % 32) * 32 + i / 32] = W2v[i];
    for (int i = t; i < 32 * 68; i += 1024) {
        int o = i / 68, j = i % 68;
        if (j < 34) W1sT[j * 32 + o] = W1e[i];
        else        W1dT[(j - 34) * 32 + o] = W1e[i];
    }
    for (int i = t; i < 32 * 32; i += 1024) {
        unsigned int u = __float_as_uint(W2e[i]);
        u += 0x7fffu + ((u >> 16) & 1u);
        W2eb[i] = (unsigned short)(u >> 16);
    }
    for (int i = t; i < 32 * 32; i += 1024) W1oT[(i % 32) * 32 + i / 32] = W1o[i];
}

// ---------------- CSR build ----------------
__global__ __launch_bounds__(256) void count_kernel(const int* __restrict__ edges, int* __restrict__ cnt)
{
    int e = blockIdx.x * 256 + threadIdx.x;
    if (e < E) atomicAdd(&cnt[edges[E + e]], 1);
}

__global__ __launch_bounds__(1024) void scan_kernel(const int* __restrict__ cnt, int* __restrict__ offs)
{
    __shared__ int s[1024];
    int t = threadIdx.x;
    int c0 = cnt[2 * t], c1 = cnt[2 * t + 1];
    int own = c0 + c1;
    s[t] = own;
    __syncthreads();
    int v = own;
    for (int d = 1; d < 1024; d <<= 1) {
        int add = (t >= d) ? s[t - d] : 0;
        __syncthreads();
        v += add;
        s[t] = v;
        __syncthreads();
    }
    int excl = v - own;
    offs[2 * t] = excl;
    offs[2 * t + 1] = excl + c0;
    if (t == 1023) offs[2048] = v;
}

__global__ __launch_bounds__(256) void fill_kernel(
    const int* __restrict__ edges, const int* __restrict__ offs,
    int* __restrict__ cursor, int* __restrict__ elist)
{
    int e = blockIdx.x * 256 + threadIdx.x;
    if (e < E) {
        int d = edges[E + e];
        int p = atomicAdd(&cursor[d], 1);
        elist[offs[d] + p] = edges[e];
    }
}

// ---------------- vertex MLP: 2 threads/node, split by WAVE (o0 wave-uniform) ----------------
// Block = 256 thr = 4 waves: waves {0,1} = nodes 0..63 halves {0,1}, waves {2,3} =
// nodes 64..127. Weight addressing uses o0 = readfirstlane(h*16) -> stays scalar
// (s_load). Register accumulators are statically indexed (rule #20). Halves exchange
// activations via LDS columns (ping-pong), one __syncthreads per layer edge.
__global__ __launch_bounds__(256) void vertex_kernel(
    const float* __restrict__ vert,
    const float* __restrict__ Wx,  const float* __restrict__ bx,
    const float* __restrict__ Wy,  const float* __restrict__ by,
    const float* __restrict__ Wth, const float* __restrict__ bth,
    const float* __restrict__ b1c, const float* __restrict__ b2c,
    const float* __restrict__ b1v, const float* __restrict__ b2v,
    const float* __restrict__ b1e,
    const float* __restrict__ W1cT, const float* __restrict__ W2cT,
    const float* __restrict__ W1vT, const float* __restrict__ W2vT,
    const float* __restrict__ W1sT, const float* __restrict__ W1dT,
    unsigned int* __restrict__ asrc, unsigned int* __restrict__ adst)
{
    __shared__ unsigned short bufS[128 * 40];   // 10 KB, stride 80 B (<=32 feats)
    __shared__ unsigned short bufT[128 * 40];   // 10 KB
    __shared__ unsigned short bufC[128 * 72];   // 18.4 KB, stride 144 B (64 feats)
    int tid = threadIdx.x;
    int w = tid >> 6, lane = tid & 63;
    int g = w >> 1;                              // node group 0/1
    int h = w & 1;                               // output half 0/1
    int o0 = __builtin_amdgcn_readfirstlane(h << 4);
    int nl = g * 64 + lane;                      // node-local 0..127
    int idx = blockIdx.x * 128 + nl;
    unsigned short* Sc = bufS + nl * 40;
    unsigned short* Tc = bufT + nl * 40;
    unsigned short* Cc = bufC + nl * 72;

    const float* v = vert + (size_t)idx * 11;
    float qk0 = v[0], qk1 = v[1], qk2 = v[2];
    float q00 = v[3], q01 = v[4], q02 = v[5];
    float qg0 = v[6], qg1 = v[7], qg2 = v[8];
    float col0 = v[9], col1 = v[10];

    for (int cfh = 0; cfh < 2; ++cfh) {
        float a0 = cfh ? qg0 : q00;
        float a1 = cfh ? qg1 : q01;
        float a2 = cfh ? qg2 : q02;
        // pair feats 24: wave h=0 computes fx(0-7)+fy(8-15), h=1 computes fth(16-23)
        if (h == 0) {
            #pragma unroll
            for (int i = 0; i < 4; ++i) {
                ((unsigned int*)Sc)[i] = pack_bf16(
                    lrelu(qk0 * Wx[4 * i]     + a0 * Wx[4 * i + 1] + bx[2 * i]),
                    lrelu(qk0 * Wx[4 * i + 2] + a0 * Wx[4 * i + 3] + bx[2 * i + 1]));
                ((unsigned int*)Sc)[4 + i] = pack_bf16(
                    lrelu(qk1 * Wy[4 * i]     + a1 * Wy[4 * i + 1] + by[2 * i]),
                    lrelu(qk1 * Wy[4 * i + 2] + a1 * Wy[4 * i + 3] + by[2 * i + 1]));
            }
        } else {
            #pragma unroll
            for (int i = 0; i < 4; ++i) {
                ((unsigned int*)Sc)[8 + i] = pack_bf16(
                    lrelu(qk2 * Wth[4 * i]     + a2 * Wth[4 * i + 1] + bth[2 * i]),
                    lrelu(qk2 * Wth[4 * i + 2] + a2 * Wth[4 * i + 3] + bth[2 * i + 1]));
            }
        }
        __syncthreads();

        float hh[16];
        #pragma unroll
        for (int o = 0; o < 16; ++o) hh[o] = b1c[o0 + o];
        layerN16(Sc, 3, o0, W1cT, hh);               // 24 feats
        #pragma unroll
        for (int q = 0; q < 8; ++q)
            ((unsigned int*)Tc)[h * 8 + q] = pack_bf16(lrelu(hh[2 * q]), lrelu(hh[2 * q + 1]));
        __syncthreads();

        float gg[16];
        #pragma unroll
        for (int o = 0; o < 16; ++o) gg[o] = b2c[o0 + o];
        layerN16(Tc, 4, o0, W2cT, gg);               // 32 feats
        #pragma unroll
        for (int q = 0; q < 8; ++q)
            ((unsigned int*)Cc)[cfh * 16 + h * 8 + q] =
                pack_bf16(lrelu(gg[2 * q]), lrelu(gg[2 * q + 1]));
        __syncthreads();
    }

    float v1[16];
    #pragma unroll
    for (int o = 0; o < 16; ++o) v1[o] = b1v[o0 + o];
    layerN16(Cc, 8, o0, W1vT, v1);                   // 64 feats
    #pragma unroll
    for (int q = 0; q < 8; ++q)
        ((unsigned int*)Sc)[h * 8 + q] = pack_bf16(lrelu(v1[2 * q]), lrelu(v1[2 * q + 1]));
    __syncthreads();

    float v2[16];
    #pragma unroll
    for (int o = 0; o < 16; ++o) v2[o] = b2v[o0 + o];
    layerN16(Sc, 4, o0, W2vT, v2);                   // 32 feats
    #pragma unroll
    for (int q = 0; q < 8; ++q)
        ((unsigned int*)Tc)[h * 8 + q] = pack_bf16(lrelu(v2[2 * q]), lrelu(v2[2 * q + 1]));
    __syncthreads();

    float as[16], ad[16];
    #pragma unroll
    for (int o = 0; o < 16; ++o) { as[o] = 0.f; ad[o] = b1e[o0 + o]; }
    layer2N16(Tc, 4, o0, W1sT, W1dT, as, ad);        // 32 feats (vfr)
    #pragma unroll
    for (int o = 0; o < 16; ++o) {                   // feats 32,33 = col0,col1
        as[o] += col0 * W1sT[32 * 32 + o0 + o] + col1 * W1sT[33 * 32 + o0 + o];
        ad[o] += col0 * W1dT[32 * 32 + o0 + o] + col1 * W1dT[33 * 32 + o0 + o];
    }

    unsigned int* ps = asrc + ((size_t)idx << 4) + h * 8;
    unsigned int* pd = adst + ((size_t)idx << 4) + h * 8;
    #pragma unroll
    for (int q = 0; q < 8; ++q) {
        ps[q] = pack_bf16(as[2 * q], as[2 * q + 1]);
        pd[q] = pack_bf16(ad[2 * q], ad[2 * q + 1]);
    }
}

// ---------------- edge phase: LDS-staged asrc, 1024-thr blocks (16 waves -> 4/SIMD) ----------------
__global__ __launch_bounds__(1024) void edge_kernel(
    const unsigned int* __restrict__ asrc, const unsigned int* __restrict__ adst,
    const int* __restrict__ elist, const int* __restrict__ offs,
    const unsigned short* __restrict__ W2eb, const float* __restrict__ b2e,
    const float* __restrict__ W1oT, const float* __restrict__ b1o,
    const float* __restrict__ W2o,  const float* __restrict__ b2o,
    float* __restrict__ fv)
{
    __shared__ uint4 sA[NN * 4];                    // 128 KB: asrc[b], row n = sA[n*4 + grp]
    int logical = (blockIdx.x & 7) * 32 + (blockIdx.x >> 3);   // XCD swizzle
    int b = logical >> 3;
    int seg = logical & 7;
    int tid = threadIdx.x;
    int wv = tid >> 6;                              // 0..15
    int lane = tid & 63;
    int col = lane & 15;
    int grp = lane >> 4;

    const uint4* gsrc = (const uint4*)(asrc + (((size_t)b * NN) << 4));
    #pragma unroll 2
    for (int i = tid; i < NN * 4; i += 1024) sA[i] = gsrc[i];
    __syncthreads();

    union U8 { unsigned int u[4]; bf16x8 v; uint4 q; };
    U8 Bf0, Bf1;
    Bf0.q = *(const uint4*)(W2eb + col * 32 + grp * 8);
    Bf1.q = *(const uint4*)(W2eb + (col + 16) * 32 + grp * 8);
    float bias0 = b2e[col];
    float bias1 = b2e[col + 16];
    float w2oc = W2o[lane & 31];
    float b1oc = b1o[lane & 31];
    float b2oc = b2o[0];
    const unsigned int* adb = adst + (((size_t)b * NN) << 4) + grp * 4;

    int dbase = seg * 256 + wv * 16;
    for (int dd = 0; dd < 16; ++dd) {
        int d = dbase + dd;
        int start = offs[d];
        int end = offs[d + 1];

        const uint4 du = *(const uint4*)(adb + ((size_t)d << 4));
        float adr[8]; unpack8(du, adr);

        float s0 = 0.f, s1 = 0.f;
        if (end > start) {
            int src_c = elist[imin(start + col, end - 1)];
            uint4 su_c = sA[src_c * 4 + grp];
            int src_n = (start + 16 < end) ? elist[imin(start + 16 + col, end - 1)] : 0;

            for (int e0 = start; e0 < end; e0 += 16) {
                uint4 su_n = (e0 + 16 < end) ? sA[src_n * 4 + grp] : su_c;
                src_n = (e0 + 32 < end) ? elist[imin(e0 + 32 + col, end - 1)] : 0;

                float h[8];
                {
                    float lo, hi;
                    unpack_bf16(su_c.x, lo, hi);
                    h[0] = fmaxf(lo + adr[0], 0.f); h[1] = fmaxf(hi + adr[1], 0.f);
                    unpack_bf16(su_c.y, lo, hi);
                    h[2] = fmaxf(lo + adr[2], 0.f); h[3] = fmaxf(hi + adr[3], 0.f);
                    unpack_bf16(su_c.z, lo, hi);
                    h[4] = fmaxf(lo + adr[4], 0.f); h[5] = fmaxf(hi + adr[5], 0.f);
                    unpack_bf16(su_c.w, lo, hi);
                    h[6] = fmaxf(lo + adr[6], 0.f); h[7] = fmaxf(hi + adr[7], 0.f);
                }
                U8 A;
                A.u[0] = pack_bf16(h[0], h[1]);
                A.u[1] = pack_bf16(h[2], h[3]);
                A.u[2] = pack_bf16(h[4], h[5]);
                A.u[3] = pack_bf16(h[6], h[7]);

                f32x4 acc0 = {bias0, bias0, bias0, bias0};
                f32x4 acc1 = {bias1, bias1, bias1, bias1};
                acc0 = __builtin_amdgcn_mfma_f32_16x16x32_bf16(A.v, Bf0.v, acc0, 0, 0, 0);
                acc1 = __builtin_amdgcn_mfma_f32_16x16x32_bf16(A.v, Bf1.v, acc1, 0, 0, 0);

                int rowbase = e0 + grp * 4;
                #pragma unroll
                for (int r = 0; r < 4; ++r) {
                    bool valid = (rowbase + r) < end;
                    s0 += valid ? lrelu(acc0[r]) : 0.f;
                    s1 += valid ? lrelu(acc1[r]) : 0.f;
                }
                su_c = su_n;
            }
        }

        s0 += __shfl_xor(s0, 16); s0 += __shfl_xor(s0, 32);
        s1 += __shfl_xor(s1, 16); s1 += __shfl_xor(s1, 32);

        float inv = 1.f / fmaxf((float)(end - start), 1.f);
        float a0 = s0 * inv;
        float a1 = s1 * inv;
        int o = lane & 31;
        float f1 = b1oc;
        #pragma unroll
        for (int j = 0; j < 16; ++j) {
            float aj = __shfl(a0, j);
            f1 += aj * W1oT[j * 32 + o];
            float ak = __shfl(a1, j);
            f1 += ak * W1oT[(16 + j) * 32 + o];
        }
        float tt = fmaxf(f1, 0.f) * w2oc;
        tt += __shfl_xor(tt, 1);
        tt += __shfl_xor(tt, 2);
        tt += __shfl_xor(tt, 4);
        tt += __shfl_xor(tt, 8);
        tt += __shfl_xor(tt, 16);
        if (lane == 0) fv[(size_t)b * NN + d] = lrelu(tt + b2oc);
    }
}

// ---------------- final: out[b] = sigmoid(dot(fv[b,:], Wg) + bg) ----------------
__global__ __launch_bounds__(256) void final_kernel(
    const float* __restrict__ fv, const float* __restrict__ Wg,
    const float* __restrict__ bg, float* __restrict__ out)
{
    int b = blockIdx.x;
    int t = threadIdx.x;
    float p = 0.f;
    for (int n = t; n < NN; n += 256) p += fv[(size_t)b * NN + n] * Wg[n];
    __shared__ float red[256];
    red[t] = p;
    __syncthreads();
    for (int s = 128; s > 0; s >>= 1) {
        if (t < s) red[t] += red[t + s];
        __syncthreads();
    }
    if (t == 0) {
        float x = red[0] + bg[0];
        out[b] = 1.f / (1.f + expf(-x));
    }
}

extern "C" void kernel_launch(void* const* d_in, const int* in_sizes, int n_in,
                              void* d_out, int out_size, void* d_ws, size_t ws_size,
                              hipStream_t stream)
{
    const float* vert = (const float*)d_in[0];
    const int*   edges = (const int*)d_in[1];
    const float* Wx  = (const float*)d_in[2];
    const float* bx  = (const float*)d_in[3];
    const float* Wy  = (const float*)d_in[4];
    const float* by  = (const float*)d_in[5];
    const float* Wth = (const float*)d_in[6];
    const float* bth = (const float*)d_in[7];
    const float* W1c = (const float*)d_in[8];
    const float* b1c = (const float*)d_in[9];
    const float* W2c = (const float*)d_in[10];
    const float* b2c = (const float*)d_in[11];
    const float* W1v = (const float*)d_in[12];
    const float* b1v = (const float*)d_in[13];
    const float* W2v = (const float*)d_in[14];
    const float* b2v = (const float*)d_in[15];
    const float* W1e = (const float*)d_in[16];
    const float* b1e = (const float*)d_in[17];
    const float* W2e = (const float*)d_in[18];
    const float* b2e = (const float*)d_in[19];
    const float* W1o = (const float*)d_in[20];
    const float* b1o = (const float*)d_in[21];
    const float* W2o = (const float*)d_in[22];
    const float* b2o = (const float*)d_in[23];
    const float* Wg  = (const float*)d_in[24];
    const float* bg  = (const float*)d_in[25];
    float* out = (float*)d_out;

    // workspace layout (~9 MB, all chunks 16B-aligned)
    char* w = (char*)d_ws;
    unsigned int* asrc = (unsigned int*)w; w += (size_t)B * NN * 32 * 2;  // bf16 pairs
    unsigned int* adst = (unsigned int*)w; w += (size_t)B * NN * 32 * 2;
    float* fv   = (float*)w; w += (size_t)B * NN * 4;
    float* W1cT = (float*)w; w += 32 * 24 * 4;
    float* W2cT = (float*)w; w += 32 * 32 * 4;
    float* W1vT = (float*)w; w += 32 * 64 * 4;
    float* W2vT = (float*)w; w += 32 * 32 * 4;
    float* W1sT = (float*)w; w += 34 * 32 * 4;
    float* W1dT = (float*)w; w += 34 * 32 * 4;
    float* W1oT = (float*)w; w += 32 * 32 * 4;
    unsigned short* W2eb = (unsigned short*)w; w += 32 * 32 * 2;
    int* cnt    = (int*)w;   w += NN * 4;
    int* cursor = (int*)w;   w += NN * 4;
    int* offs   = (int*)w;   w += 2052 * 4;
    int* elist  = (int*)w;   w += E * 4;

    prep_zero_kernel<<<12, 256, 0, stream>>>(W1c, W2c, W1v, W2v, W1e, W2e, W1o,
                                             W1cT, W2cT, W1vT, W2vT, W1sT, W1dT,
                                             W2eb, W1oT, cnt, cursor);
    count_kernel<<<E / 256, 256, 0, stream>>>(edges, cnt);
    scan_kernel<<<1, 1024, 0, stream>>>(cnt, offs);
    fill_kernel<<<E / 256, 256, 0, stream>>>(edges, offs, cursor, elist);

    vertex_kernel<<<(B * NN) / 128, 256, 0, stream>>>(
        vert, Wx, bx, Wy, by, Wth, bth, b1c, b2c, b1v, b2v, b1e,
        W1cT, W2cT, W1vT, W2vT, W1sT, W1dT, asrc, adst);

    edge_kernel<<<B * 8, 1024, 0, stream>>>(
        asrc, adst, elist, offs, W2eb, b2e, W1oT, b1o, W2o, b2o, fv);

    final_kernel<<<B, 256, 0, stream>>>(fv, Wg, bg, out);
}

// Round 11
// 114.693 us; speedup vs baseline: 2.2227x; 1.1092x over previous
//
#include <hip/hip_runtime.h>
#include <math.h>

constexpr int B = 32;
constexpr int NN = 2048;   // nodes
constexpr int E = 65536;   // edges
constexpr float SLOPE = 0.01f;

typedef __attribute__((ext_vector_type(8))) short bf16x8;
typedef __attribute__((ext_vector_type(4))) float f32x4;

// lrelu(x) = max(x, 0.01x)  -- 2 VALU instr (valid for slope in (0,1))
__device__ __forceinline__ float lrelu(float x) { return fmaxf(x, SLOPE * x); }
__device__ __forceinline__ int imin(int a, int b) { return a < b ? a : b; }

// single-instruction pack of 2 f32 -> 2 bf16 (RNE); low half = first operand
__device__ __forceinline__ unsigned int cvtpk(float lo, float hi) {
    unsigned int r;
    asm("v_cvt_pk_bf16_f32 %0, %1, %2" : "=v"(r) : "v"(lo), "v"(hi));
    return r;
}

__device__ __forceinline__ void unpack_bf16(unsigned int u, float& lo, float& hi) {
    lo = __uint_as_float(u << 16);
    hi = __uint_as_float(u & 0xffff0000u);
}

__device__ __forceinline__ void unpack8(const uint4& u, float f[8]) {
    unpack_bf16(u.x, f[0], f[1]);
    unpack_bf16(u.y, f[2], f[3]);
    unpack_bf16(u.z, f[4], f[5]);
    unpack_bf16(u.w, f[6], f[7]);
}

// ---- 16-output-half layer helpers (o0 is wave-uniform SGPR via readfirstlane) ----
__device__ __forceinline__ void fma_grp16(const float* __restrict__ Wt, int jj, int o0,
                                          const uint4& r, float acc[16]) {
    float x[8]; unpack8(r, x);
    const float* Wp = Wt + jj * 256 + o0;
    #pragma unroll
    for (int jo = 0; jo < 8; ++jo) {
        #pragma unroll
        for (int o = 0; o < 16; ++o) acc[o] += x[jo] * Wp[jo * 32 + o];
    }
}

__device__ __forceinline__ void layerN16(const unsigned short* col, int G, int o0,
                                         const float* __restrict__ Wt, float acc[16]) {
    uint4 cur = *(const uint4*)col;
    #pragma unroll 1
    for (int jj = 0; jj < G; ++jj) {
        uint4 nxt = (jj + 1 < G) ? *(const uint4*)(col + (jj + 1) * 8) : cur;
        fma_grp16(Wt, jj, o0, cur, acc);
        cur = nxt;
    }
}

__device__ __forceinline__ void layer2N16(const unsigned short* col, int G, int o0,
                                          const float* __restrict__ Ws,
                                          const float* __restrict__ Wd,
                                          float a1[16], float a2[16]) {
    uint4 cur = *(const uint4*)col;
    #pragma unroll 1
    for (int jj = 0; jj < G; ++jj) {
        uint4 nxt = (jj + 1 < G) ? *(const uint4*)(col + (jj + 1) * 8) : cur;
        float x[8]; unpack8(cur, x);
        const float* Wps = Ws + jj * 256 + o0;
        const float* Wpd = Wd + jj * 256 + o0;
        #pragma unroll
        for (int jo = 0; jo < 8; ++jo) {
            #pragma unroll
            for (int o = 0; o < 16; ++o) a1[o] += x[jo] * Wps[jo * 32 + o];
            #pragma unroll
            for (int o = 0; o < 16; ++o) a2[o] += x[jo] * Wpd[jo * 32 + o];
        }
        cur = nxt;
    }
}

// ---------------- prep (blocks 8..11) + CSR-counter zero (blocks 0..7) ----------------
__global__ __launch_bounds__(256) void prep_zero_kernel(
    const float* __restrict__ W1c, const float* __restrict__ W2c,
    const float* __restrict__ W1v, const float* __restrict__ W2v,
    const float* __restrict__ W1e, const float* __restrict__ W2e,
    const float* __restrict__ W1o,
    float* __restrict__ W1cT, float* __restrict__ W2cT,
    float* __restrict__ W1vT, float* __restrict__ W2vT,
    float* __restrict__ W1sT, float* __restrict__ W1dT,
    unsigned short* __restrict__ W2eb, float* __restrict__ W1oT,
    int* __restrict__ cnt, int* __restrict__ cursor)
{
    int blk = blockIdx.x;
    if (blk < 8) {
        int i = blk * 256 + threadIdx.x;
        cnt[i] = 0;
        cursor[i] = 0;
        return;
    }
    int t = (blk - 8) * 256 + threadIdx.x;         // 0..1023
    for (int i = t; i < 32 * 24; i += 1024) W1cT[(i % 24) * 32 + i / 24] = W1c[i];
    for (int i = t; i < 32 * 32; i += 1024) W2cT[(i % 32) * 32 + i / 32] = W2c[i];
    for (int i = t; i < 32 * 64; i += 1024) W1vT[(i % 64) * 32 + i / 64] = W1v[i];
    for (int i = t; i < 32 * 32; i += 1024) W2vT[(i % 32) * 32 + i / 32] = W2v[i];
    for (int i = t; i < 32 * 68; i += 1024) {
        int o = i / 68, j = i % 68;
        if (j < 34) W1sT[j * 32 + o] = W1e[i];
        else        W1dT[(j - 34) * 32 + o] = W1e[i];
    }
    for (int i = t; i < 32 * 32; i += 1024) {
        unsigned int u = __float_as_uint(W2e[i]);
        u += 0x7fffu + ((u >> 16) & 1u);
        W2eb[i] = (unsigned short)(u >> 16);
    }
    for (int i = t; i < 32 * 32; i += 1024) W1oT[(i % 32) * 32 + i / 32] = W1o[i];
}

// ---------------- CSR build ----------------
__global__ __launch_bounds__(256) void count_kernel(const int* __restrict__ edges, int* __restrict__ cnt)
{
    int e = blockIdx.x * 256 + threadIdx.x;
    if (e < E) atomicAdd(&cnt[edges[E + e]], 1);
}

__global__ __launch_bounds__(1024) void scan_kernel(const int* __restrict__ cnt, int* __restrict__ offs)
{
    __shared__ int s[1024];
    int t = threadIdx.x;
    int c0 = cnt[2 * t], c1 = cnt[2 * t + 1];
    int own = c0 + c1;
    s[t] = own;
    __syncthreads();
    int v = own;
    for (int d = 1; d < 1024; d <<= 1) {
        int add = (t >= d) ? s[t - d] : 0;
        __syncthreads();
        v += add;
        s[t] = v;
        __syncthreads();
    }
    int excl = v - own;
    offs[2 * t] = excl;
    offs[2 * t + 1] = excl + c0;
    if (t == 1023) offs[2048] = v;
}

__global__ __launch_bounds__(256) void fill_kernel(
    const int* __restrict__ edges, const int* __restrict__ offs,
    int* __restrict__ cursor, int* __restrict__ elist)
{
    int e = blockIdx.x * 256 + threadIdx.x;
    if (e < E) {
        int d = edges[E + e];
        int p = atomicAdd(&cursor[d], 1);
        elist[offs[d] + p] = edges[e];
    }
}

// ---------------- vertex MLP: 2 threads/node, split by WAVE (o0 wave-uniform) ----------------
__global__ __launch_bounds__(256) void vertex_kernel(
    const float* __restrict__ vert,
    const float* __restrict__ Wx,  const float* __restrict__ bx,
    const float* __restrict__ Wy,  const float* __restrict__ by,
    const float* __restrict__ Wth, const float* __restrict__ bth,
    const float* __restrict__ b1c, const float* __restrict__ b2c,
    const float* __restrict__ b1v, const float* __restrict__ b2v,
    const float* __restrict__ b1e,
    const float* __restrict__ W1cT, const float* __restrict__ W2cT,
    const float* __restrict__ W1vT, const float* __restrict__ W2vT,
    const float* __restrict__ W1sT, const float* __restrict__ W1dT,
    unsigned int* __restrict__ asrc, unsigned int* __restrict__ adst)
{
    __shared__ unsigned short bufS[128 * 40];   // 10 KB, stride 80 B (<=32 feats)
    __shared__ unsigned short bufT[128 * 40];   // 10 KB
    __shared__ unsigned short bufC[128 * 72];   // 18.4 KB, stride 144 B (64 feats)
    int tid = threadIdx.x;
    int w = tid >> 6, lane = tid & 63;
    int g = w >> 1;                              // node group 0/1
    int h = w & 1;                               // output half 0/1
    int o0 = __builtin_amdgcn_readfirstlane(h << 4);
    int nl = g * 64 + lane;                      // node-local 0..127
    int idx = blockIdx.x * 128 + nl;
    unsigned short* Sc = bufS + nl * 40;
    unsigned short* Tc = bufT + nl * 40;
    unsigned short* Cc = bufC + nl * 72;

    const float* v = vert + (size_t)idx * 11;
    float qk0 = v[0], qk1 = v[1], qk2 = v[2];
    float q00 = v[3], q01 = v[4], q02 = v[5];
    float qg0 = v[6], qg1 = v[7], qg2 = v[8];
    float col0 = v[9], col1 = v[10];

    for (int cfh = 0; cfh < 2; ++cfh) {
        float a0 = cfh ? qg0 : q00;
        float a1 = cfh ? qg1 : q01;
        float a2 = cfh ? qg2 : q02;
        if (h == 0) {
            #pragma unroll
            for (int i = 0; i < 4; ++i) {
                ((unsigned int*)Sc)[i] = cvtpk(
                    lrelu(qk0 * Wx[4 * i]     + a0 * Wx[4 * i + 1] + bx[2 * i]),
                    lrelu(qk0 * Wx[4 * i + 2] + a0 * Wx[4 * i + 3] + bx[2 * i + 1]));
                ((unsigned int*)Sc)[4 + i] = cvtpk(
                    lrelu(qk1 * Wy[4 * i]     + a1 * Wy[4 * i + 1] + by[2 * i]),
                    lrelu(qk1 * Wy[4 * i + 2] + a1 * Wy[4 * i + 3] + by[2 * i + 1]));
            }
        } else {
            #pragma unroll
            for (int i = 0; i < 4; ++i) {
                ((unsigned int*)Sc)[8 + i] = cvtpk(
                    lrelu(qk2 * Wth[4 * i]     + a2 * Wth[4 * i + 1] + bth[2 * i]),
                    lrelu(qk2 * Wth[4 * i + 2] + a2 * Wth[4 * i + 3] + bth[2 * i + 1]));
            }
        }
        __syncthreads();

        float hh[16];
        #pragma unroll
        for (int o = 0; o < 16; ++o) hh[o] = b1c[o0 + o];
        layerN16(Sc, 3, o0, W1cT, hh);               // 24 feats
        #pragma unroll
        for (int q = 0; q < 8; ++q)
            ((unsigned int*)Tc)[h * 8 + q] = cvtpk(lrelu(hh[2 * q]), lrelu(hh[2 * q + 1]));
        __syncthreads();

        float gg[16];
        #pragma unroll
        for (int o = 0; o < 16; ++o) gg[o] = b2c[o0 + o];
        layerN16(Tc, 4, o0, W2cT, gg);               // 32 feats
        #pragma unroll
        for (int q = 0; q < 8; ++q)
            ((unsigned int*)Cc)[cfh * 16 + h * 8 + q] =
                cvtpk(lrelu(gg[2 * q]), lrelu(gg[2 * q + 1]));
        __syncthreads();
    }

    float v1[16];
    #pragma unroll
    for (int o = 0; o < 16; ++o) v1[o] = b1v[o0 + o];
    layerN16(Cc, 8, o0, W1vT, v1);                   // 64 feats
    #pragma unroll
    for (int q = 0; q < 8; ++q)
        ((unsigned int*)Sc)[h * 8 + q] = cvtpk(lrelu(v1[2 * q]), lrelu(v1[2 * q + 1]));
    __syncthreads();

    float v2[16];
    #pragma unroll
    for (int o = 0; o < 16; ++o) v2[o] = b2v[o0 + o];
    layerN16(Sc, 4, o0, W2vT, v2);                   // 32 feats
    #pragma unroll
    for (int q = 0; q < 8; ++q)
        ((unsigned int*)Tc)[h * 8 + q] = cvtpk(lrelu(v2[2 * q]), lrelu(v2[2 * q + 1]));
    __syncthreads();

    float as[16], ad[16];
    #pragma unroll
    for (int o = 0; o < 16; ++o) { as[o] = 0.f; ad[o] = b1e[o0 + o]; }
    layer2N16(Tc, 4, o0, W1sT, W1dT, as, ad);        // 32 feats (vfr)
    #pragma unroll
    for (int o = 0; o < 16; ++o) {                   // feats 32,33 = col0,col1
        as[o] += col0 * W1sT[32 * 32 + o0 + o] + col1 * W1sT[33 * 32 + o0 + o];
        ad[o] += col0 * W1dT[32 * 32 + o0 + o] + col1 * W1dT[33 * 32 + o0 + o];
    }

    unsigned int* ps = asrc + ((size_t)idx << 4) + h * 8;
    unsigned int* pd = adst + ((size_t)idx << 4) + h * 8;
    #pragma unroll
    for (int q = 0; q < 8; ++q) {
        ps[q] = cvtpk(as[2 * q], as[2 * q + 1]);
        pd[q] = cvtpk(ad[2 * q], ad[2 * q + 1]);
    }
}

// ---------------- edge phase: LDS-staged asrc, 1024-thr blocks, lean inner loop ----------------
// Invalid chunk rows: A fragment zeroed -> D row = bias exactly; accumulate all rows
// unconditionally and subtract (padded-deg)*lrelu(bias) after the wave reduce.
__global__ __launch_bounds__(1024) void edge_kernel(
    const unsigned int* __restrict__ asrc, const unsigned int* __restrict__ adst,
    const int* __restrict__ elist, const int* __restrict__ offs,
    const unsigned short* __restrict__ W2eb, const float* __restrict__ b2e,
    const float* __restrict__ W1oT, const float* __restrict__ b1o,
    const float* __restrict__ W2o,  const float* __restrict__ b2o,
    float* __restrict__ fv)
{
    __shared__ uint4 sA[NN * 4];                    // 128 KB: asrc[b], row n = sA[n*4 + grp]
    int logical = (blockIdx.x & 7) * 32 + (blockIdx.x >> 3);   // XCD swizzle
    int b = logical >> 3;
    int seg = logical & 7;
    int tid = threadIdx.x;
    int wv = tid >> 6;                              // 0..15
    int lane = tid & 63;
    int col = lane & 15;
    int grp = lane >> 4;

    const uint4* gsrc = (const uint4*)(asrc + (((size_t)b * NN) << 4));
    #pragma unroll 2
    for (int i = tid; i < NN * 4; i += 1024) sA[i] = gsrc[i];
    __syncthreads();

    union U8 { unsigned int u[4]; bf16x8 v; uint4 q; };
    U8 Bf0, Bf1;
    Bf0.q = *(const uint4*)(W2eb + col * 32 + grp * 8);
    Bf1.q = *(const uint4*)(W2eb + (col + 16) * 32 + grp * 8);
    float bias0 = b2e[col];
    float bias1 = b2e[col + 16];
    float lb0 = lrelu(bias0);                       // exact invalid-row contribution
    float lb1 = lrelu(bias1);
    int o = lane & 31;
    float w2oc = W2o[o];
    float b1oc = b1o[o];
    float b2oc = b2o[0];
    float w1or[32];                                 // W1o column cached in registers
    #pragma unroll
    for (int j = 0; j < 32; ++j) w1or[j] = W1oT[j * 32 + o];
    const unsigned int* adb = adst + (((size_t)b * NN) << 4) + grp * 4;

    int dbase = seg * 256 + wv * 16;
    for (int dd = 0; dd < 16; ++dd) {
        int d = dbase + dd;
        int start = offs[d];
        int end = offs[d + 1];
        int deg = end - start;

        const uint4 du = *(const uint4*)(adb + ((size_t)d << 4));
        float adr[8]; unpack8(du, adr);

        float s0 = 0.f, s1 = 0.f;
        if (deg > 0) {
            int src_c = elist[imin(start + col, end - 1)];
            uint4 su_c = sA[src_c * 4 + grp];
            int src_n = (start + 16 < end) ? elist[imin(start + 16 + col, end - 1)] : 0;

            for (int e0 = start; e0 < end; e0 += 16) {
                uint4 su_n = (e0 + 16 < end) ? sA[src_n * 4 + grp] : su_c;
                src_n = (e0 + 32 < end) ? elist[imin(e0 + 32 + col, end - 1)] : 0;

                float h0, h1, h2, h3, h4, h5, h6, h7;
                {
                    float lo, hi;
                    unpack_bf16(su_c.x, lo, hi);
                    h0 = fmaxf(lo + adr[0], 0.f); h1 = fmaxf(hi + adr[1], 0.f);
                    unpack_bf16(su_c.y, lo, hi);
                    h2 = fmaxf(lo + adr[2], 0.f); h3 = fmaxf(hi + adr[3], 0.f);
                    unpack_bf16(su_c.z, lo, hi);
                    h4 = fmaxf(lo + adr[4], 0.f); h5 = fmaxf(hi + adr[5], 0.f);
                    unpack_bf16(su_c.w, lo, hi);
                    h6 = fmaxf(lo + adr[6], 0.f); h7 = fmaxf(hi + adr[7], 0.f);
                }
                U8 A;
                A.u[0] = cvtpk(h0, h1);
                A.u[1] = cvtpk(h2, h3);
                A.u[2] = cvtpk(h4, h5);
                A.u[3] = cvtpk(h6, h7);
                if ((e0 + col) >= end) {            // zero this lane's A row (1 cmp + 4 sel)
                    A.u[0] = 0; A.u[1] = 0; A.u[2] = 0; A.u[3] = 0;
                }

                f32x4 acc0 = {bias0, bias0, bias0, bias0};
                f32x4 acc1 = {bias1, bias1, bias1, bias1};
                acc0 = __builtin_amdgcn_mfma_f32_16x16x32_bf16(A.v, Bf0.v, acc0, 0, 0, 0);
                acc1 = __builtin_amdgcn_mfma_f32_16x16x32_bf16(A.v, Bf1.v, acc1, 0, 0, 0);

                #pragma unroll
                for (int r = 0; r < 4; ++r) {       // unconditional: 2 instr lrelu + add
                    s0 += lrelu(acc0[r]);
                    s1 += lrelu(acc1[r]);
                }
                su_c = su_n;
            }
        }

        s0 += __shfl_xor(s0, 16); s0 += __shfl_xor(s0, 32);
        s1 += __shfl_xor(s1, 16); s1 += __shfl_xor(s1, 32);

        int padded = ((deg + 15) >> 4) << 4;        // rows actually pushed through MFMA
        float pad = (float)(padded - deg);
        s0 -= pad * lb0;
        s1 -= pad * lb1;

        float inv = 1.f / fmaxf((float)deg, 1.f);
        float a0 = s0 * inv;
        float a1 = s1 * inv;
        float f1 = b1oc;
        #pragma unroll
        for (int j = 0; j < 16; ++j) {
            f1 += __shfl(a0, j) * w1or[j];
            f1 += __shfl(a1, j) * w1or[16 + j];
        }
        float tt = fmaxf(f1, 0.f) * w2oc;
        tt += __shfl_xor(tt, 1);
        tt += __shfl_xor(tt, 2);
        tt += __shfl_xor(tt, 4);
        tt += __shfl_xor(tt, 8);
        tt += __shfl_xor(tt, 16);
        if (lane == 0) fv[(size_t)b * NN + d] = lrelu(tt + b2oc);
    }
}

// ---------------- final: out[b] = sigmoid(dot(fv[b,:], Wg) + bg) ----------------
__global__ __launch_bounds__(256) void final_kernel(
    const float* __restrict__ fv, const float* __restrict__ Wg,
    const float* __restrict__ bg, float* __restrict__ out)
{
    int b = blockIdx.x;
    int t = threadIdx.x;
    float p = 0.f;
    for (int n = t; n < NN; n += 256) p += fv[(size_t)b * NN + n] * Wg[n];
    __shared__ float red[256];
    red[t] = p;
    __syncthreads();
    for (int s = 128; s > 0; s >>= 1) {
        if (t < s) red[t] += red[t + s];
        __syncthreads();
    }
    if (t == 0) {
        float x = red[0] + bg[0];
        out[b] = 1.f / (1.f + expf(-x));
    }
}

extern "C" void kernel_launch(void* const* d_in, const int* in_sizes, int n_in,
                              void* d_out, int out_size, void* d_ws, size_t ws_size,
                              hipStream_t stream)
{
    const float* vert = (const float*)d_in[0];
    const int*   edges = (const int*)d_in[1];
    const float* Wx  = (const float*)d_in[2];
    const float* bx  = (const float*)d_in[3];
    const float* Wy  = (const float*)d_in[4];
    const float* by  = (const float*)d_in[5];
    const float* Wth = (const float*)d_in[6];
    const float* bth = (const float*)d_in[7];
    const float* W1c = (const float*)d_in[8];
    const float* b1c = (const float*)d_in[9];
    const float* W2c = (const float*)d_in[10];
    const float* b2c = (const float*)d_in[11];
    const float* W1v = (const float*)d_in[12];
    const float* b1v = (const float*)d_in[13];
    const float* W2v = (const float*)d_in[14];
    const float* b2v = (const float*)d_in[15];
    const float* W1e = (const float*)d_in[16];
    const float* b1e = (const float*)d_in[17];
    const float* W2e = (const float*)d_in[18];
    const float* b2e = (const float*)d_in[19];
    const float* W1o = (const float*)d_in[20];
    const float* b1o = (const float*)d_in[21];
    const float* W2o = (const float*)d_in[22];
    const float* b2o = (const float*)d_in[23];
    const float* Wg  = (const float*)d_in[24];
    const float* bg  = (const float*)d_in[25];
    float* out = (float*)d_out;

    // workspace layout (~9 MB, all chunks 16B-aligned)
    char* w = (char*)d_ws;
    unsigned int* asrc = (unsigned int*)w; w += (size_t)B * NN * 32 * 2;  // bf16 pairs
    unsigned int* adst = (unsigned int*)w; w += (size_t)B * NN * 32 * 2;
    float* fv   = (float*)w; w += (size_t)B * NN * 4;
    float* W1cT = (float*)w; w += 32 * 24 * 4;
    float* W2cT = (float*)w; w += 32 * 32 * 4;
    float* W1vT = (float*)w; w += 32 * 64 * 4;
    float* W2vT = (float*)w; w += 32 * 32 * 4;
    float* W1sT = (float*)w; w += 34 * 32 * 4;
    float* W1dT = (float*)w; w += 34 * 32 * 4;
    float* W1oT = (float*)w; w += 32 * 32 * 4;
    unsigned short* W2eb = (unsigned short*)w; w += 32 * 32 * 2;
    int* cnt    = (int*)w;   w += NN * 4;
    int* cursor = (int*)w;   w += NN * 4;
    int* offs   = (int*)w;   w += 2052 * 4;
    int* elist  = (int*)w;   w += E * 4;

    prep_zero_kernel<<<12, 256, 0, stream>>>(W1c, W2c, W1v, W2v, W1e, W2e, W1o,
                                             W1cT, W2cT, W1vT, W2vT, W1sT, W1dT,
                                             W2eb, W1oT, cnt, cursor);
    count_kernel<<<E / 256, 256, 0, stream>>>(edges, cnt);
    scan_kernel<<<1, 1024, 0, stream>>>(cnt, offs);
    fill_kernel<<<E / 256, 256, 0, stream>>>(edges, offs, cursor, elist);

    vertex_kernel<<<(B * NN) / 128, 256, 0, stream>>>(
        vert, Wx, bx, Wy, by, Wth, bth, b1c, b2c, b1v, b2v, b1e,
        W1cT, W2cT, W1vT, W2vT, W1sT, W1dT, asrc, adst);

    edge_kernel<<<B * 8, 1024, 0, stream>>>(
        asrc, adst, elist, offs, W2eb, b2e, W1oT, b1o, W2o, b2o, fv);

    final_kernel<<<B, 256, 0, stream>>>(fv, Wg, bg, out);
}

// Round 12
// 108.078 us; speedup vs baseline: 2.3587x; 1.0612x over previous
//
#include <hip/hip_runtime.h>
#include <math.h>

constexpr int B = 32;
constexpr int NN = 2048;   // nodes
constexpr int E = 65536;   // edges
constexpr float SLOPE = 0.01f;

typedef __attribute__((ext_vector_type(8))) short bf16x8;
typedef __attribute__((ext_vector_type(4))) float f32x4;

__device__ __forceinline__ float lrelu(float x) { return fmaxf(x, SLOPE * x); }
__device__ __forceinline__ int imin(int a, int b) { return a < b ? a : b; }
__device__ __forceinline__ int imax(int a, int b) { return a > b ? a : b; }

// single-instruction pack of 2 f32 -> 2 bf16 (RNE); low half = first operand
__device__ __forceinline__ unsigned int cvtpk(float lo, float hi) {
    unsigned int r;
    asm("v_cvt_pk_bf16_f32 %0, %1, %2" : "=v"(r) : "v"(lo), "v"(hi));
    return r;
}

__device__ __forceinline__ void unpack_bf16(unsigned int u, float& lo, float& hi) {
    lo = __uint_as_float(u << 16);
    hi = __uint_as_float(u & 0xffff0000u);
}

__device__ __forceinline__ void unpack8(const uint4& u, float f[8]) {
    unpack_bf16(u.x, f[0], f[1]);
    unpack_bf16(u.y, f[2], f[3]);
    unpack_bf16(u.z, f[4], f[5]);
    unpack_bf16(u.w, f[6], f[7]);
}

union U8 { unsigned int u[4]; bf16x8 v; uint4 q; };

// LDS quad swizzle: quad q of row n stored at n*4 + (q ^ sw(n))
__device__ __forceinline__ int swz(int n) { return (n ^ (n >> 2)) & 3; }

// ---- 16-output-half layer helpers (vertex kernel; o0 wave-uniform SGPR) ----
__device__ __forceinline__ void fma_grp16(const float* __restrict__ Wt, int jj, int o0,
                                          const uint4& r, float acc[16]) {
    float x[8]; unpack8(r, x);
    const float* Wp = Wt + jj * 256 + o0;
    #pragma unroll
    for (int jo = 0; jo < 8; ++jo) {
        #pragma unroll
        for (int o = 0; o < 16; ++o) acc[o] += x[jo] * Wp[jo * 32 + o];
    }
}

__device__ __forceinline__ void layerN16(const unsigned short* col, int G, int o0,
                                         const float* __restrict__ Wt, float acc[16]) {
    uint4 cur = *(const uint4*)col;
    #pragma unroll 1
    for (int jj = 0; jj < G; ++jj) {
        uint4 nxt = (jj + 1 < G) ? *(const uint4*)(col + (jj + 1) * 8) : cur;
        fma_grp16(Wt, jj, o0, cur, acc);
        cur = nxt;
    }
}

__device__ __forceinline__ void layer2N16(const unsigned short* col, int G, int o0,
                                          const float* __restrict__ Ws,
                                          const float* __restrict__ Wd,
                                          float a1[16], float a2[16]) {
    uint4 cur = *(const uint4*)col;
    #pragma unroll 1
    for (int jj = 0; jj < G; ++jj) {
        uint4 nxt = (jj + 1 < G) ? *(const uint4*)(col + (jj + 1) * 8) : cur;
        float x[8]; unpack8(cur, x);
        const float* Wps = Ws + jj * 256 + o0;
        const float* Wpd = Wd + jj * 256 + o0;
        #pragma unroll
        for (int jo = 0; jo < 8; ++jo) {
            #pragma unroll
            for (int o = 0; o < 16; ++o) a1[o] += x[jo] * Wps[jo * 32 + o];
            #pragma unroll
            for (int o = 0; o < 16; ++o) a2[o] += x[jo] * Wpd[jo * 32 + o];
        }
        cur = nxt;
    }
}

// ---------------- prep (blocks 8..11) + CSR-counter zero (blocks 0..7) ----------------
__global__ __launch_bounds__(256) void prep_zero_kernel(
    const float* __restrict__ W1c, const float* __restrict__ W2c,
    const float* __restrict__ W1v, const float* __restrict__ W2v,
    const float* __restrict__ W1e, const float* __restrict__ W2e,
    const float* __restrict__ W1o,
    float* __restrict__ W1cT, float* __restrict__ W2cT,
    float* __restrict__ W1vT, float* __restrict__ W2vT,
    float* __restrict__ W1sT, float* __restrict__ W1dT,
    unsigned short* __restrict__ W2eb, float* __restrict__ W1oT,
    int* __restrict__ cnt, int* __restrict__ cursor)
{
    int blk = blockIdx.x;
    if (blk < 8) {
        int i = blk * 256 + threadIdx.x;
        cnt[i] = 0;
        cursor[i] = 0;
        return;
    }
    int t = (blk - 8) * 256 + threadIdx.x;         // 0..1023
    for (int i = t; i < 32 * 24; i += 1024) W1cT[(i % 24) * 32 + i / 24] = W1c[i];
    for (int i = t; i < 32 * 32; i += 1024) W2cT[(i % 32) * 32 + i / 32] = W2c[i];
    for (int i = t; i < 32 * 64; i += 1024) W1vT[(i % 64) * 32 + i / 64] = W1v[i];
    for (int i = t; i < 32 * 32; i += 1024) W2vT[(i % 32) * 32 + i / 32] = W2v[i];
    for (int i = t; i < 32 * 68; i += 1024) {
        int o = i / 68, j = i % 68;
        if (j < 34) W1sT[j * 32 + o] = W1e[i];
        else        W1dT[(j - 34) * 32 + o] = W1e[i];
    }
    for (int i = t; i < 32 * 32; i += 1024) {
        unsigned int u = __float_as_uint(W2e[i]);
        u += 0x7fffu + ((u >> 16) & 1u);
        W2eb[i] = (unsigned short)(u >> 16);
    }
    for (int i = t; i < 32 * 32; i += 1024) W1oT[(i % 32) * 32 + i / 32] = W1o[i];
}

// ---------------- CSR build ----------------
__global__ __launch_bounds__(256) void count_kernel(const int* __restrict__ edges, int* __restrict__ cnt)
{
    int e = blockIdx.x * 256 + threadIdx.x;
    if (e < E) atomicAdd(&cnt[edges[E + e]], 1);
}

__global__ __launch_bounds__(1024) void scan_kernel(const int* __restrict__ cnt, int* __restrict__ offs)
{
    __shared__ int s[1024];
    int t = threadIdx.x;
    int c0 = cnt[2 * t], c1 = cnt[2 * t + 1];
    int own = c0 + c1;
    s[t] = own;
    __syncthreads();
    int v = own;
    for (int d = 1; d < 1024; d <<= 1) {
        int add = (t >= d) ? s[t - d] : 0;
        __syncthreads();
        v += add;
        s[t] = v;
        __syncthreads();
    }
    int excl = v - own;
    offs[2 * t] = excl;
    offs[2 * t + 1] = excl + c0;
    if (t == 1023) offs[2048] = v;
}

__global__ __launch_bounds__(256) void fill_kernel(
    const int* __restrict__ edges, const int* __restrict__ offs,
    int* __restrict__ cursor, int* __restrict__ elist)
{
    int e = blockIdx.x * 256 + threadIdx.x;
    if (e < E) {
        int d = edges[E + e];
        int p = atomicAdd(&cursor[d], 1);
        elist[offs[d] + p] = edges[e];
    }
}

// ---------------- vertex MLP: 2 threads/node, split by WAVE (unchanged r11) ----------------
__global__ __launch_bounds__(256) void vertex_kernel(
    const float* __restrict__ vert,
    const float* __restrict__ Wx,  const float* __restrict__ bx,
    const float* __restrict__ Wy,  const float* __restrict__ by,
    const float* __restrict__ Wth, const float* __restrict__ bth,
    const float* __restrict__ b1c, const float* __restrict__ b2c,
    const float* __restrict__ b1v, const float* __restrict__ b2v,
    const float* __restrict__ b1e,
    const float* __restrict__ W1cT, const float* __restrict__ W2cT,
    const float* __restrict__ W1vT, const float* __restrict__ W2vT,
    const float* __restrict__ W1sT, const float* __restrict__ W1dT,
    unsigned int* __restrict__ asrc, unsigned int* __restrict__ adst)
{
    __shared__ unsigned short bufS[128 * 40];   // 10 KB, stride 80 B
    __shared__ unsigned short bufT[128 * 40];   // 10 KB
    __shared__ unsigned short bufC[128 * 72];   // 18.4 KB, stride 144 B
    int tid = threadIdx.x;
    int w = tid >> 6, lane = tid & 63;
    int g = w >> 1;
    int h = w & 1;
    int o0 = __builtin_amdgcn_readfirstlane(h << 4);
    int nl = g * 64 + lane;
    int idx = blockIdx.x * 128 + nl;
    unsigned short* Sc = bufS + nl * 40;
    unsigned short* Tc = bufT + nl * 40;
    unsigned short* Cc = bufC + nl * 72;

    const float* v = vert + (size_t)idx * 11;
    float qk0 = v[0], qk1 = v[1], qk2 = v[2];
    float q00 = v[3], q01 = v[4], q02 = v[5];
    float qg0 = v[6], qg1 = v[7], qg2 = v[8];
    float col0 = v[9], col1 = v[10];

    for (int cfh = 0; cfh < 2; ++cfh) {
        float a0 = cfh ? qg0 : q00;
        float a1 = cfh ? qg1 : q01;
        float a2 = cfh ? qg2 : q02;
        if (h == 0) {
            #pragma unroll
            for (int i = 0; i < 4; ++i) {
                ((unsigned int*)Sc)[i] = cvtpk(
                    lrelu(qk0 * Wx[4 * i]     + a0 * Wx[4 * i + 1] + bx[2 * i]),
                    lrelu(qk0 * Wx[4 * i + 2] + a0 * Wx[4 * i + 3] + bx[2 * i + 1]));
                ((unsigned int*)Sc)[4 + i] = cvtpk(
                    lrelu(qk1 * Wy[4 * i]     + a1 * Wy[4 * i + 1] + by[2 * i]),
                    lrelu(qk1 * Wy[4 * i + 2] + a1 * Wy[4 * i + 3] + by[2 * i + 1]));
            }
        } else {
            #pragma unroll
            for (int i = 0; i < 4; ++i) {
                ((unsigned int*)Sc)[8 + i] = cvtpk(
                    lrelu(qk2 * Wth[4 * i]     + a2 * Wth[4 * i + 1] + bth[2 * i]),
                    lrelu(qk2 * Wth[4 * i + 2] + a2 * Wth[4 * i + 3] + bth[2 * i + 1]));
            }
        }
        __syncthreads();

        float hh[16];
        #pragma unroll
        for (int o = 0; o < 16; ++o) hh[o] = b1c[o0 + o];
        layerN16(Sc, 3, o0, W1cT, hh);
        #pragma unroll
        for (int q = 0; q < 8; ++q)
            ((unsigned int*)Tc)[h * 8 + q] = cvtpk(lrelu(hh[2 * q]), lrelu(hh[2 * q + 1]));
        __syncthreads();

        float gg[16];
        #pragma unroll
        for (int o = 0; o < 16; ++o) gg[o] = b2c[o0 + o];
        layerN16(Tc, 4, o0, W2cT, gg);
        #pragma unroll
        for (int q = 0; q < 8; ++q)
            ((unsigned int*)Cc)[cfh * 16 + h * 8 + q] =
                cvtpk(lrelu(gg[2 * q]), lrelu(gg[2 * q + 1]));
        __syncthreads();
    }

    float v1[16];
    #pragma unroll
    for (int o = 0; o < 16; ++o) v1[o] = b1v[o0 + o];
    layerN16(Cc, 8, o0, W1vT, v1);
    #pragma unroll
    for (int q = 0; q < 8; ++q)
        ((unsigned int*)Sc)[h * 8 + q] = cvtpk(lrelu(v1[2 * q]), lrelu(v1[2 * q + 1]));
    __syncthreads();

    float v2[16];
    #pragma unroll
    for (int o = 0; o < 16; ++o) v2[o] = b2v[o0 + o];
    layerN16(Sc, 4, o0, W2vT, v2);
    #pragma unroll
    for (int q = 0; q < 8; ++q)
        ((unsigned int*)Tc)[h * 8 + q] = cvtpk(lrelu(v2[2 * q]), lrelu(v2[2 * q + 1]));
    __syncthreads();

    float as[16], ad[16];
    #pragma unroll
    for (int o = 0; o < 16; ++o) { as[o] = 0.f; ad[o] = b1e[o0 + o]; }
    layer2N16(Tc, 4, o0, W1sT, W1dT, as, ad);
    #pragma unroll
    for (int o = 0; o < 16; ++o) {
        as[o] += col0 * W1sT[32 * 32 + o0 + o] + col1 * W1sT[33 * 32 + o0 + o];
        ad[o] += col0 * W1dT[32 * 32 + o0 + o] + col1 * W1dT[33 * 32 + o0 + o];
    }

    unsigned int* ps = asrc + ((size_t)idx << 4) + h * 8;
    unsigned int* pd = adst + ((size_t)idx << 4) + h * 8;
    #pragma unroll
    for (int q = 0; q < 8; ++q) {
        ps[q] = cvtpk(as[2 * q], as[2 * q + 1]);
        pd[q] = cvtpk(ad[2 * q], ad[2 * q + 1]);
    }
}

// ---- one 16-edge chunk step for one dst stream (straight-line, inlined) ----
__device__ __forceinline__ void chunk_step(
    const uint4* __restrict__ sA, const int* __restrict__ elist,
    int e0, int end, int e1, int col, int grp,
    uint4& su_c, int& src_n, const float adr[8],
    const U8& Bf0, const U8& Bf1, float bias0, float bias1,
    float& s0, float& s1)
{
    // prefetch next chunk's gather + next-next elist
    uint4 su_n = sA[(src_n << 2) | (grp ^ swz(src_n))];
    int src_n2 = elist[imin(e0 + 32 + col, e1)];

    float h0, h1, h2, h3, h4, h5, h6, h7;
    {
        float lo, hi;
        unpack_bf16(su_c.x, lo, hi);
        h0 = fmaxf(lo + adr[0], 0.f); h1 = fmaxf(hi + adr[1], 0.f);
        unpack_bf16(su_c.y, lo, hi);
        h2 = fmaxf(lo + adr[2], 0.f); h3 = fmaxf(hi + adr[3], 0.f);
        unpack_bf16(su_c.z, lo, hi);
        h4 = fmaxf(lo + adr[4], 0.f); h5 = fmaxf(hi + adr[5], 0.f);
        unpack_bf16(su_c.w, lo, hi);
        h6 = fmaxf(lo + adr[6], 0.f); h7 = fmaxf(hi + adr[7], 0.f);
    }
    U8 A;
    A.u[0] = cvtpk(h0, h1);
    A.u[1] = cvtpk(h2, h3);
    A.u[2] = cvtpk(h4, h5);
    A.u[3] = cvtpk(h6, h7);
    if ((e0 + col) >= end) {            // zero invalid lane's A row
        A.u[0] = 0; A.u[1] = 0; A.u[2] = 0; A.u[3] = 0;
    }

    f32x4 acc0 = {bias0, bias0, bias0, bias0};
    f32x4 acc1 = {bias1, bias1, bias1, bias1};
    acc0 = __builtin_amdgcn_mfma_f32_16x16x32_bf16(A.v, Bf0.v, acc0, 0, 0, 0);
    acc1 = __builtin_amdgcn_mfma_f32_16x16x32_bf16(A.v, Bf1.v, acc1, 0, 0, 0);

    #pragma unroll
    for (int r = 0; r < 4; ++r) {
        s0 += lrelu(acc0[r]);
        s1 += lrelu(acc1[r]);
    }
    su_c = su_n;
    src_n = src_n2;
}

// ---------------- edge phase: LDS-staged (swizzled) asrc, 1024-thr blocks,
//                  TWO interleaved dst streams per wave ----------------
__global__ __launch_bounds__(1024) void edge_kernel(
    const unsigned int* __restrict__ asrc, const unsigned int* __restrict__ adst,
    const int* __restrict__ elist, const int* __restrict__ offs,
    const unsigned short* __restrict__ W2eb, const float* __restrict__ b2e,
    const float* __restrict__ W1oT, const float* __restrict__ b1o,
    const float* __restrict__ W2o,  const float* __restrict__ b2o,
    float* __restrict__ fv)
{
    __shared__ uint4 sA[NN * 4];                    // 128 KB, quad-swizzled rows
    int logical = (blockIdx.x & 7) * 32 + (blockIdx.x >> 3);   // XCD swizzle
    int b = logical >> 3;
    int seg = logical & 7;
    int tid = threadIdx.x;
    int wv = tid >> 6;
    int lane = tid & 63;
    int col = lane & 15;
    int grp = lane >> 4;

    // stage asrc[b] -> LDS with quad swizzle (write: quad q of row n -> n*4 + (q^swz(n)))
    const uint4* gsrc = (const uint4*)(asrc + (((size_t)b * NN) << 4));
    #pragma unroll 2
    for (int i = tid; i < NN * 4; i += 1024) {
        int n = i >> 2, q = i & 3;
        sA[(n << 2) | (q ^ swz(n))] = gsrc[i];
    }
    __syncthreads();

    U8 Bf0, Bf1;
    Bf0.q = *(const uint4*)(W2eb + col * 32 + grp * 8);
    Bf1.q = *(const uint4*)(W2eb + (col + 16) * 32 + grp * 8);
    float bias0 = b2e[col];
    float bias1 = b2e[col + 16];
    float lb0 = lrelu(bias0);
    float lb1 = lrelu(bias1);
    int o = lane & 31;
    float w2oc = W2o[o];
    float b1oc = b1o[o];
    float b2oc = b2o[0];
    float w1or[32];
    #pragma unroll
    for (int j = 0; j < 32; ++j) w1or[j] = W1oT[j * 32 + o];
    const unsigned int* adb = adst + (((size_t)b * NN) << 4) + grp * 4;

    int dbase = seg * 256 + wv * 16;
    for (int dp = 0; dp < 8; ++dp) {
        int dA = dbase + 2 * dp;
        int dB = dA + 1;
        int startA = offs[dA];
        int endA = offs[dB];
        int endB = offs[dB + 1];
        int startB = endA;
        int degA = endA - startA;
        int degB = endB - startB;
        int e1A = imax(endA - 1, 0);                // clamped last-valid elist index
        int e1B = imax(endB - 1, 0);

        const uint4 duA = *(const uint4*)(adb + ((size_t)dA << 4));
        const uint4 duB = *(const uint4*)(adb + ((size_t)dB << 4));
        float adrA[8]; unpack8(duA, adrA);
        float adrB[8]; unpack8(duB, adrB);

        int n = imax((degA + 15) >> 4, (degB + 15) >> 4);

        float s0A = 0.f, s1A = 0.f, s0B = 0.f, s1B = 0.f;
        if (n > 0) {
            int srcA = elist[imin(startA + col, e1A)];
            int srcB = elist[imin(startB + col, e1B)];
            uint4 suA = sA[(srcA << 2) | (grp ^ swz(srcA))];
            uint4 suB = sA[(srcB << 2) | (grp ^ swz(srcB))];
            int srcnA = elist[imin(startA + 16 + col, e1A)];
            int srcnB = elist[imin(startB + 16 + col, e1B)];

            for (int it = 0; it < n; ++it) {
                int e0A = startA + (it << 4);
                int e0B = startB + (it << 4);
                chunk_step(sA, elist, e0A, endA, e1A, col, grp,
                           suA, srcnA, adrA, Bf0, Bf1, bias0, bias1, s0A, s1A);
                chunk_step(sA, elist, e0B, endB, e1B, col, grp,
                           suB, srcnB, adrB, Bf0, Bf1, bias0, bias1, s0B, s1B);
            }
        }

        s0A += __shfl_xor(s0A, 16); s0A += __shfl_xor(s0A, 32);
        s1A += __shfl_xor(s1A, 16); s1A += __shfl_xor(s1A, 32);
        s0B += __shfl_xor(s0B, 16); s0B += __shfl_xor(s0B, 32);
        s1B += __shfl_xor(s1B, 16); s1B += __shfl_xor(s1B, 32);

        // both streams ran n chunks = 16n rows; subtract exact bias rows
        float padA = (float)(16 * n - degA);
        float padB = (float)(16 * n - degB);
        s0A -= padA * lb0; s1A -= padA * lb1;
        s0B -= padB * lb0; s1B -= padB * lb1;

        float invA = 1.f / fmaxf((float)degA, 1.f);
        float invB = 1.f / fmaxf((float)degB, 1.f);
        float a0A = s0A * invA, a1A = s1A * invA;
        float a0B = s0B * invB, a1B = s1B * invB;

        // node MLP for both dsts, 4-partial trees (static j&3 indexing)
        float pA[4] = {b1oc, 0.f, 0.f, 0.f};
        float pB[4] = {b1oc, 0.f, 0.f, 0.f};
        #pragma unroll
        for (int j = 0; j < 16; ++j) {
            pA[j & 3] += __shfl(a0A, j) * w1or[j];
            pA[j & 3] += __shfl(a1A, j) * w1or[16 + j];
            pB[j & 3] += __shfl(a0B, j) * w1or[j];
            pB[j & 3] += __shfl(a1B, j) * w1or[16 + j];
        }
        float f1A = (pA[0] + pA[1]) + (pA[2] + pA[3]);
        float f1B = (pB[0] + pB[1]) + (pB[2] + pB[3]);

        float tA = fmaxf(f1A, 0.f) * w2oc;
        float tB = fmaxf(f1B, 0.f) * w2oc;
        tA += __shfl_xor(tA, 1);  tB += __shfl_xor(tB, 1);
        tA += __shfl_xor(tA, 2);  tB += __shfl_xor(tB, 2);
        tA += __shfl_xor(tA, 4);  tB += __shfl_xor(tB, 4);
        tA += __shfl_xor(tA, 8);  tB += __shfl_xor(tB, 8);
        tA += __shfl_xor(tA, 16); tB += __shfl_xor(tB, 16);
        if (lane == 0) {
            fv[(size_t)b * NN + dA] = lrelu(tA + b2oc);
            fv[(size_t)b * NN + dB] = lrelu(tB + b2oc);
        }
    }
}

// ---------------- final: out[b] = sigmoid(dot(fv[b,:], Wg) + bg) ----------------
__global__ __launch_bounds__(256) void final_kernel(
    const float* __restrict__ fv, const float* __restrict__ Wg,
    const float* __restrict__ bg, float* __restrict__ out)
{
    int b = blockIdx.x;
    int t = threadIdx.x;
    float p = 0.f;
    for (int n = t; n < NN; n += 256) p += fv[(size_t)b * NN + n] * Wg[n];
    __shared__ float red[256];
    red[t] = p;
    __syncthreads();
    for (int s = 128; s > 0; s >>= 1) {
        if (t < s) red[t] += red[t + s];
        __syncthreads();
    }
    if (t == 0) {
        float x = red[0] + bg[0];
        out[b] = 1.f / (1.f + expf(-x));
    }
}

extern "C" void kernel_launch(void* const* d_in, const int* in_sizes, int n_in,
                              void* d_out, int out_size, void* d_ws, size_t ws_size,
                              hipStream_t stream)
{
    const float* vert = (const float*)d_in[0];
    const int*   edges = (const int*)d_in[1];
    const float* Wx  = (const float*)d_in[2];
    const float* bx  = (const float*)d_in[3];
    const float* Wy  = (const float*)d_in[4];
    const float* by  = (const float*)d_in[5];
    const float* Wth = (const float*)d_in[6];
    const float* bth = (const float*)d_in[7];
    const float* W1c = (const float*)d_in[8];
    const float* b1c = (const float*)d_in[9];
    const float* W2c = (const float*)d_in[10];
    const float* b2c = (const float*)d_in[11];
    const float* W1v = (const float*)d_in[12];
    const float* b1v = (const float*)d_in[13];
    const float* W2v = (const float*)d_in[14];
    const float* b2v = (const float*)d_in[15];
    const float* W1e = (const float*)d_in[16];
    const float* b1e = (const float*)d_in[17];
    const float* W2e = (const float*)d_in[18];
    const float* b2e = (const float*)d_in[19];
    const float* W1o = (const float*)d_in[20];
    const float* b1o = (const float*)d_in[21];
    const float* W2o = (const float*)d_in[22];
    const float* b2o = (const float*)d_in[23];
    const float* Wg  = (const float*)d_in[24];
    const float* bg  = (const float*)d_in[25];
    float* out = (float*)d_out;

    // workspace layout (~9 MB, all chunks 16B-aligned)
    char* w = (char*)d_ws;
    unsigned int* asrc = (unsigned int*)w; w += (size_t)B * NN * 32 * 2;  // bf16 pairs
    unsigned int* adst = (unsigned int*)w; w += (size_t)B * NN * 32 * 2;
    float* fv   = (float*)w; w += (size_t)B * NN * 4;
    float* W1cT = (float*)w; w += 32 * 24 * 4;
    float* W2cT = (float*)w; w += 32 * 32 * 4;
    float* W1vT = (float*)w; w += 32 * 64 * 4;
    float* W2vT = (float*)w; w += 32 * 32 * 4;
    float* W1sT = (float*)w; w += 34 * 32 * 4;
    float* W1dT = (float*)w; w += 34 * 32 * 4;
    float* W1oT = (float*)w; w += 32 * 32 * 4;
    unsigned short* W2eb = (unsigned short*)w; w += 32 * 32 * 2;
    int* cnt    = (int*)w;   w += NN * 4;
    int* cursor = (int*)w;   w += NN * 4;
    int* offs   = (int*)w;   w += 2052 * 4;
    int* elist  = (int*)w;   w += E * 4;

    prep_zero_kernel<<<12, 256, 0, stream>>>(W1c, W2c, W1v, W2v, W1e, W2e, W1o,
                                             W1cT, W2cT, W1vT, W2vT, W1sT, W1dT,
                                             W2eb, W1oT, cnt, cursor);
    count_kernel<<<E / 256, 256, 0, stream>>>(edges, cnt);
    scan_kernel<<<1, 1024, 0, stream>>>(cnt, offs);
    fill_kernel<<<E / 256, 256, 0, stream>>>(edges, offs, cursor, elist);

    vertex_kernel<<<(B * NN) / 128, 256, 0, stream>>>(
        vert, Wx, bx, Wy, by, Wth, bth, b1c, b2c, b1v, b2v, b1e,
        W1cT, W2cT, W1vT, W2vT, W1sT, W1dT, asrc, adst);

    edge_kernel<<<B * 8, 1024, 0, stream>>>(
        asrc, adst, elist, offs, W2eb, b2e, W1oT, b1o, W2o, b2o, fv);

    final_kernel<<<B, 256, 0, stream>>>(fv, Wg, bg, out);
}